// Round 9
// baseline (364.324 us; speedup 1.0000x reference)
//
#include <hip/hip_runtime.h>
#include <hip/hip_fp16.h>

#define BEPS 1e-5f
static constexpr int TPB = 256;
static constexpr int G_SC = 512;      // scatter workgroups
static constexpr int BK_SHIFT = 8;    // bucket = 256-node range
static constexpr int BK_NODES = 256;
static constexpr int KMAX = 512;      // max buckets (N <= 131072)
static constexpr int BK_SLACK = 2048; // per-bucket colidx padding slack

union F4H8 { float4 f4; __half2 h2[4]; };  // 16B = 8 halfs

typedef _Float16 half8 __attribute__((ext_vector_type(8)));
typedef float floatx4 __attribute__((ext_vector_type(4)));

// ================= CSR build: two-level bucket counting sort =================

__global__ __launch_bounds__(TPB) void k_zero_int(int* __restrict__ p, int n) {
  int i = blockIdx.x * TPB + threadIdx.x;
  if (i < n) p[i] = 0;
}

// int4-vectorized edge reads (R9: 4x fewer load instrs on the 6.4MB stream)
__global__ __launch_bounds__(TPB) void k_hist(const int* __restrict__ dst,
                                              int* __restrict__ histG,
                                              int* __restrict__ btot,
                                              int E, int K, int chunk) {
  __shared__ int lh[KMAX];
  int g = blockIdx.x, t = threadIdx.x;
  for (int i = t; i < KMAX; i += TPB) lh[i] = 0;
  __syncthreads();
  int e0 = g * chunk, e1 = min(E, e0 + chunk);
  for (int e = e0 + t * 4; e < e1; e += TPB * 4) {
    if (e + 4 <= e1) {
      int4 d4 = *reinterpret_cast<const int4*>(dst + e);
      atomicAdd(&lh[d4.x >> BK_SHIFT], 1);
      atomicAdd(&lh[d4.y >> BK_SHIFT], 1);
      atomicAdd(&lh[d4.z >> BK_SHIFT], 1);
      atomicAdd(&lh[d4.w >> BK_SHIFT], 1);
    } else {
      for (int q = e; q < e1; ++q) atomicAdd(&lh[dst[q] >> BK_SHIFT], 1);
    }
  }
  __syncthreads();
  for (int i = t; i < K; i += TPB) {
    histG[i * G_SC + g] = lh[i];
    atomicAdd(&btot[i], lh[i]);
  }
}

__global__ __launch_bounds__(KMAX) void k_bbase(const int* __restrict__ btot,
                                                int* __restrict__ bbase, int K) {
  __shared__ int sh[KMAX];
  int t = threadIdx.x;
  int v = (t < K) ? btot[t] : 0;
  sh[t] = v;
  __syncthreads();
  for (int s = 1; s < KMAX; s <<= 1) {
    int x = sh[t];
    int y = (t >= s) ? sh[t - s] : 0;
    __syncthreads();
    sh[t] = x + y;
    __syncthreads();
  }
  if (t < K) bbase[t] = sh[t] - v;
  if (t == 0) bbase[K] = sh[K - 1];
}

__global__ __launch_bounds__(G_SC) void k_offs(const int* __restrict__ histG,
                                               const int* __restrict__ bbase,
                                               int* __restrict__ offs) {
  __shared__ int sh[G_SC];
  int b = blockIdx.x, t = threadIdx.x;
  int v = histG[b * G_SC + t];
  sh[t] = v;
  __syncthreads();
  for (int s = 1; s < G_SC; s <<= 1) {
    int x = sh[t];
    int y = (t >= s) ? sh[t - s] : 0;
    __syncthreads();
    sh[t] = x + y;
    __syncthreads();
  }
  offs[b * G_SC + t] = bbase[b] + sh[t] - v;
}

__global__ __launch_bounds__(TPB) void k_scatter(const int* __restrict__ src,
                                                 const int* __restrict__ dst,
                                                 const int* __restrict__ offs,
                                                 unsigned int* __restrict__ pairs,
                                                 int E, int K, int chunk) {
  __shared__ int cur[KMAX];
  int g = blockIdx.x, t = threadIdx.x;
  for (int i = t; i < K; i += TPB) cur[i] = offs[i * G_SC + g];
  __syncthreads();
  int e0 = g * chunk, e1 = min(E, e0 + chunk);
  for (int e = e0 + t * 4; e < e1; e += TPB * 4) {
    if (e + 4 <= e1) {
      int4 d4 = *reinterpret_cast<const int4*>(dst + e);
      int4 s4 = *reinterpret_cast<const int4*>(src + e);
      int p0 = atomicAdd(&cur[d4.x >> BK_SHIFT], 1);
      pairs[p0] = (unsigned int)s4.x | ((unsigned int)(d4.x & (BK_NODES - 1)) << 20);
      int p1 = atomicAdd(&cur[d4.y >> BK_SHIFT], 1);
      pairs[p1] = (unsigned int)s4.y | ((unsigned int)(d4.y & (BK_NODES - 1)) << 20);
      int p2 = atomicAdd(&cur[d4.z >> BK_SHIFT], 1);
      pairs[p2] = (unsigned int)s4.z | ((unsigned int)(d4.z & (BK_NODES - 1)) << 20);
      int p3 = atomicAdd(&cur[d4.w >> BK_SHIFT], 1);
      pairs[p3] = (unsigned int)s4.w | ((unsigned int)(d4.w & (BK_NODES - 1)) << 20);
    } else {
      for (int q = e; q < e1; ++q) {
        int d = dst[q];
        int pos = atomicAdd(&cur[d >> BK_SHIFT], 1);
        pairs[pos] = (unsigned int)src[q] | ((unsigned int)(d & (BK_NODES - 1)) << 20);
      }
    }
  }
}

// per-bucket LDS counting sort -> PADDED colidx (lists padded to multiple of 8
// with sentinel N -> zero row; 8-aligned starts; tail-free agg loops).
__global__ __launch_bounds__(TPB) void k_bucket_sort(const unsigned int* __restrict__ pairs,
                                                     const int* __restrict__ bbase,
                                                     int* __restrict__ rowptr,
                                                     int* __restrict__ rowend,
                                                     int* __restrict__ colidx,
                                                     float* __restrict__ dinv,
                                                     int N, int E) {
  __shared__ int cur[BK_NODES];
  __shared__ int sh[BK_NODES];
  int b = blockIdx.x, t = threadIdx.x;
  int base = bbase[b], end = bbase[b + 1];
  int n0 = b << BK_SHIFT;
  int nNodes = min(BK_NODES, N - n0);
  cur[t] = 0;
  __syncthreads();
  for (int e = base + t; e < end; e += TPB) atomicAdd(&cur[pairs[e] >> 20], 1);
  __syncthreads();
  int v = cur[t];                 // raw degree
  int pd = (v + 7) & ~7;          // padded degree
  sh[t] = pd;
  __syncthreads();
  for (int s = 1; s < TPB; s <<= 1) {
    int x = sh[t];
    int y = (t >= s) ? sh[t - s] : 0;
    __syncthreads();
    sh[t] = x + y;
    __syncthreads();
  }
  int Bb = (base + b * BK_SLACK + 7) & ~7;
  int start = Bb + (sh[t] - pd);
  if (t < nNodes) {
    rowptr[n0 + t] = start;
    rowend[n0 + t] = start + pd;
    dinv[n0 + t] = rsqrtf((float)(v + 1));
    for (int i = start + v; i < start + pd; ++i) colidx[i] = N;  // pads -> zero row
  }
  __syncthreads();
  cur[t] = start;
  __syncthreads();
  for (int e = base + t; e < end; e += TPB) {
    unsigned int p = pairs[e];
    int pos = atomicAdd(&cur[p >> 20], 1);
    colidx[pos] = (int)(p & 0xFFFFFu);
  }
}

// ================= W pack (all 5 weights) + bufA zero-row init =================
__device__ inline void packone(const float* __restrict__ W, _Float16* __restrict__ Wp,
                               int i, int FO) {
  int j = i & 7, lane = (i >> 3) & 63, tile = i >> 9;
  int nct = FO >> 4, ct = tile % nct, kch = tile / nct;
  int k = kch * 32 + ((lane >> 4) << 3) + j;
  int n = (ct << 4) + (lane & 15);
  Wp[i] = (_Float16)W[k * FO + n];
}

__global__ __launch_bounds__(TPB) void k_packAll(const float* w1, _Float16* p1,
                                                 const float* w2, _Float16* p2,
                                                 const float* w3, _Float16* p3,
                                                 const float* w4, _Float16* p4,
                                                 const float* w5, _Float16* p5,
                                                 __half* bufA, int N) {
  int i = blockIdx.x * TPB + threadIdx.x;
  if (i < 8192) packone(w1, p1, i, 64);
  else if (i < 16384) packone(w2, p2, i - 8192, 128);
  else if (i < 24576) packone(w3, p3, i - 16384, 64);
  else if (i < 26624) packone(w4, p4, i - 24576, 32);
  else if (i < 27136) packone(w5, p5, i - 26624, 16);
  else if (i < 27144) {  // zero bufA's F=64 sentinel row N
    float4 z = {0.f, 0.f, 0.f, 0.f};
    reinterpret_cast<float4*>(bufA + (size_t)64 * N)[i - 27136] = z;
  }
}

// ================= MFMA GEMM (L1 only) =================
template <int FI, int FO, int EPI, bool F32IN>
__global__ __launch_bounds__(TPB) void k_mgemm(const void* __restrict__ hin,
                                               const _Float16* __restrict__ Wp,
                                               const float* __restrict__ dinv,
                                               const float* __restrict__ bias,
                                               const float* __restrict__ g,
                                               const float* __restrict__ be,
                                               const float* __restrict__ m,
                                               const float* __restrict__ v,
                                               __half* __restrict__ out, int N) {
  constexpr int NCT = FO / 16;
  constexpr int NKC = FI / 32;
  __shared__ float4 Wsh[NKC * NCT * 64];
  for (int i = threadIdx.x; i < NKC * NCT * 64; i += TPB)
    Wsh[i] = reinterpret_cast<const float4*>(Wp)[i];
  __syncthreads();

  int lane = threadIdx.x & 63;
  int wv = threadIdx.x >> 6;
  int quad = lane >> 4;
  int rowBase = blockIdx.x * 64 + wv * 16;
  int rA = min(rowBase + (lane & 15), N - 1);

  floatx4 acc[NCT];
#pragma unroll
  for (int ct = 0; ct < NCT; ++ct) acc[ct] = (floatx4){0.f, 0.f, 0.f, 0.f};

#pragma unroll
  for (int kch = 0; kch < NKC; ++kch) {
    half8 a;
    if constexpr (F32IN) {
      const float4* xp = reinterpret_cast<const float4*>(hin);
      size_t idx = ((size_t)rA * FI + kch * 32 + quad * 8) >> 2;
      float4 fa = xp[idx], fb = xp[idx + 1];
      a[0] = (_Float16)fa.x; a[1] = (_Float16)fa.y; a[2] = (_Float16)fa.z; a[3] = (_Float16)fa.w;
      a[4] = (_Float16)fb.x; a[5] = (_Float16)fb.y; a[6] = (_Float16)fb.z; a[7] = (_Float16)fb.w;
    } else {
      union { float4 f4; half8 h8; } ua;
      ua.f4 = reinterpret_cast<const float4*>(hin)[((size_t)rA * FI + kch * 32 + quad * 8) >> 3];
      a = ua.h8;
    }
#pragma unroll
    for (int ct = 0; ct < NCT; ++ct) {
      union { float4 f4; half8 h8; } ub;
      ub.f4 = Wsh[(kch * NCT + ct) * 64 + lane];
      acc[ct] = __builtin_amdgcn_mfma_f32_16x16x32_f16(a, ub.h8, acc[ct], 0, 0, 0);
    }
  }

  int r0 = rowBase + quad * 4;
  float dv[4];
#pragma unroll
  for (int reg = 0; reg < 4; ++reg) dv[reg] = (r0 + reg < N) ? dinv[r0 + reg] : 0.f;
#pragma unroll
  for (int ct = 0; ct < NCT; ++ct) {
    int col = ct * 16 + (lane & 15);
#pragma unroll
    for (int reg = 0; reg < 4; ++reg) {
      int r = r0 + reg;
      out[(size_t)r * FO + col] = __float2half(acc[ct][reg] * dv[reg]);
    }
  }
  (void)bias; (void)g; (void)be; (void)m; (void)v;
}

// ======== Fused AGG -> A-fragment gather (FI=64) ========
// Key identity: mfma A-frag (m=lane&15, k=kch*32+quad*8+j) means lane (m,quad)
// holds granules g = kch*4+quad of row m. So per-edge 16B granule gathers land
// DIRECTLY in A-layout; aggregation output never touches memory.
// BN<0>: afr = dv*acc (plain).  BN<1>: afr = relu(bn(dv*acc + bias)).
template <int DO_BN>
__device__ inline void agg_gather64(const float4* __restrict__ in16,
                                    const int* __restrict__ rowptr,
                                    const int* __restrict__ rowend,
                                    const int* __restrict__ colidx,
                                    const float* __restrict__ dinv,
                                    const float* __restrict__ b_,
                                    const float* __restrict__ g_,
                                    const float* __restrict__ be_,
                                    const float* __restrict__ m_,
                                    const float* __restrict__ v_,
                                    int node, int quad, int N, half8 afr[2]) {
  bool valid = node < N;
  int rd = valid ? node : N;
  int e0 = valid ? rowptr[node] : 0;
  int e1 = valid ? rowend[node] : 0;
  float acc[2][8];
#pragma unroll
  for (int kch = 0; kch < 2; ++kch) {
    F4H8 u;
    u.f4 = in16[(size_t)rd * 8 + kch * 4 + quad];
#pragma unroll
    for (int i = 0; i < 4; ++i) {
      float2 t2 = __half22float2(u.h2[i]);
      acc[kch][2 * i] = t2.x;
      acc[kch][2 * i + 1] = t2.y;
    }
  }
  for (int e = e0; e < e1; e += 4) {
    int4 c = *reinterpret_cast<const int4*>(colidx + e);
#pragma unroll
    for (int kch = 0; kch < 2; ++kch) {
      int g = kch * 4 + quad;
      F4H8 u0, u1, u2, u3;
      u0.f4 = in16[(size_t)c.x * 8 + g];
      u1.f4 = in16[(size_t)c.y * 8 + g];
      u2.f4 = in16[(size_t)c.z * 8 + g];
      u3.f4 = in16[(size_t)c.w * 8 + g];
#pragma unroll
      for (int i = 0; i < 4; ++i) {
        float2 a = __half22float2(u0.h2[i]), b = __half22float2(u1.h2[i]);
        float2 cc = __half22float2(u2.h2[i]), d = __half22float2(u3.h2[i]);
        acc[kch][2 * i] += (a.x + b.x) + (cc.x + d.x);
        acc[kch][2 * i + 1] += (a.y + b.y) + (cc.y + d.y);
      }
    }
  }
  float dv = valid ? dinv[node] : 0.f;
#pragma unroll
  for (int kch = 0; kch < 2; ++kch) {
    int f0 = kch * 32 + quad * 8;
#pragma unroll
    for (int j = 0; j < 8; ++j) {
      float val = acc[kch][j] * dv;
      if (DO_BN) {
        int f = f0 + j;
        float sc = g_[f] * rsqrtf(v_[f] + BEPS);
        val = fmaxf((val + b_[f] - m_[f]) * sc + be_[f], 0.f);
      }
      afr[kch][j] = (_Float16)val;
    }
  }
}

// ====== Fused L2 chain: gather(agg) -> 64->128 BN2/ReLU -> 128->64 *dinv ======
__global__ __launch_bounds__(TPB) void k_aggemm23(const __half* __restrict__ hin,
                                                  const int* __restrict__ rowptr,
                                                  const int* __restrict__ rowend,
                                                  const int* __restrict__ colidx,
                                                  const _Float16* __restrict__ W2p,
                                                  const _Float16* __restrict__ W3p,
                                                  const float* __restrict__ dinv,
                                                  const float* __restrict__ b2,
                                                  const float* __restrict__ g2,
                                                  const float* __restrict__ be2,
                                                  const float* __restrict__ m2,
                                                  const float* __restrict__ v2,
                                                  __half* __restrict__ out, int N) {
  __shared__ float4 W2s[2 * 8 * 64];       // 16 KB
  __shared__ float4 W3s[4 * 4 * 64];       // 16 KB
  __shared__ _Float16 tr[4 * 16 * 136];    // 17 KB
  for (int i = threadIdx.x; i < 1024; i += TPB) W2s[i] = reinterpret_cast<const float4*>(W2p)[i];
  for (int i = threadIdx.x; i < 1024; i += TPB) W3s[i] = reinterpret_cast<const float4*>(W3p)[i];
  __syncthreads();

  int lane = threadIdx.x & 63;
  int wv = threadIdx.x >> 6;
  int quad = lane >> 4;
  int m = lane & 15;
  int rowBase = blockIdx.x * 64 + wv * 16;

  half8 afr[2];
  agg_gather64<0>(reinterpret_cast<const float4*>(hin), rowptr, rowend, colidx, dinv,
                  nullptr, nullptr, nullptr, nullptr, nullptr, rowBase + m, quad, N, afr);

  floatx4 acc1[8];
#pragma unroll
  for (int ct = 0; ct < 8; ++ct) acc1[ct] = (floatx4){0.f, 0.f, 0.f, 0.f};
#pragma unroll
  for (int kch = 0; kch < 2; ++kch) {
#pragma unroll
    for (int ct = 0; ct < 8; ++ct) {
      union { float4 f4; half8 h8; } ub;
      ub.f4 = W2s[(kch * 8 + ct) * 64 + lane];
      acc1[ct] = __builtin_amdgcn_mfma_f32_16x16x32_f16(afr[kch], ub.h8, acc1[ct], 0, 0, 0);
    }
  }
  _Float16* mytr = tr + wv * 16 * 136;
#pragma unroll
  for (int ct = 0; ct < 8; ++ct) {
    int col = ct * 16 + m;
    float sc = g2[col] * rsqrtf(v2[col] + BEPS);
    float bb = b2[col] - m2[col];
    float ee = be2[col];
#pragma unroll
    for (int reg = 0; reg < 4; ++reg) {
      int r = quad * 4 + reg;
      mytr[r * 136 + col] = (_Float16)fmaxf((acc1[ct][reg] + bb) * sc + ee, 0.f);
    }
  }
  floatx4 acc2[4];
#pragma unroll
  for (int ct = 0; ct < 4; ++ct) acc2[ct] = (floatx4){0.f, 0.f, 0.f, 0.f};
#pragma unroll
  for (int kch = 0; kch < 4; ++kch) {
    half8 a2 = *reinterpret_cast<const half8*>(&mytr[m * 136 + kch * 32 + quad * 8]);
#pragma unroll
    for (int ct = 0; ct < 4; ++ct) {
      union { float4 f4; half8 h8; } ub;
      ub.f4 = W3s[(kch * 4 + ct) * 64 + lane];
      acc2[ct] = __builtin_amdgcn_mfma_f32_16x16x32_f16(a2, ub.h8, acc2[ct], 0, 0, 0);
    }
  }
  int r0 = rowBase + quad * 4;
  float dv[4];
#pragma unroll
  for (int reg = 0; reg < 4; ++reg) dv[reg] = (r0 + reg < N) ? dinv[r0 + reg] : 0.f;
#pragma unroll
  for (int ct = 0; ct < 4; ++ct) {
    int col = ct * 16 + m;
#pragma unroll
    for (int reg = 0; reg < 4; ++reg) {
      int r = r0 + reg;
      out[(size_t)r * 64 + col] = __float2half(acc2[ct][reg] * dv[reg]);
    }
  }
}

// ====== Fused agg(BN)+GEMM, FI=64 -> FO (L4's agg3+gemm4) ======
template <int FO>
__global__ __launch_bounds__(TPB) void k_aggemm64(const __half* __restrict__ hin,
                                                  const int* __restrict__ rowptr,
                                                  const int* __restrict__ rowend,
                                                  const int* __restrict__ colidx,
                                                  const _Float16* __restrict__ Wp,
                                                  const float* __restrict__ dinv,
                                                  const float* __restrict__ b_,
                                                  const float* __restrict__ g_,
                                                  const float* __restrict__ be_,
                                                  const float* __restrict__ m_,
                                                  const float* __restrict__ v_,
                                                  __half* __restrict__ out, int N) {
  constexpr int NCT = FO / 16;
  __shared__ float4 Wsh[2 * NCT * 64];
  for (int i = threadIdx.x; i < 2 * NCT * 64; i += TPB)
    Wsh[i] = reinterpret_cast<const float4*>(Wp)[i];
  __syncthreads();

  int lane = threadIdx.x & 63;
  int wv = threadIdx.x >> 6;
  int quad = lane >> 4;
  int m = lane & 15;
  int rowBase = blockIdx.x * 64 + wv * 16;

  half8 afr[2];
  agg_gather64<1>(reinterpret_cast<const float4*>(hin), rowptr, rowend, colidx, dinv,
                  b_, g_, be_, m_, v_, rowBase + m, quad, N, afr);

  floatx4 acc[NCT];
#pragma unroll
  for (int ct = 0; ct < NCT; ++ct) acc[ct] = (floatx4){0.f, 0.f, 0.f, 0.f};
#pragma unroll
  for (int kch = 0; kch < 2; ++kch) {
#pragma unroll
    for (int ct = 0; ct < NCT; ++ct) {
      union { float4 f4; half8 h8; } ub;
      ub.f4 = Wsh[(kch * NCT + ct) * 64 + lane];
      acc[ct] = __builtin_amdgcn_mfma_f32_16x16x32_f16(afr[kch], ub.h8, acc[ct], 0, 0, 0);
    }
  }
  int r0 = rowBase + quad * 4;
  float dv[4];
#pragma unroll
  for (int reg = 0; reg < 4; ++reg) dv[reg] = (r0 + reg < N) ? dinv[r0 + reg] : 0.f;
#pragma unroll
  for (int ct = 0; ct < NCT; ++ct) {
    int col = ct * 16 + m;
#pragma unroll
    for (int reg = 0; reg < 4; ++reg) {
      int r = r0 + reg;
      out[(size_t)r * FO + col] = __float2half(acc[ct][reg] * dv[reg]);
    }
  }
}

// ====== Fused agg(BN)+GEMM, FI=32 -> FO=16 (L5's agg4+gemm5) ======
__global__ __launch_bounds__(TPB) void k_aggemm5(const __half* __restrict__ hin,
                                                 const int* __restrict__ rowptr,
                                                 const int* __restrict__ rowend,
                                                 const int* __restrict__ colidx,
                                                 const _Float16* __restrict__ Wp,
                                                 const float* __restrict__ dinv,
                                                 const float* __restrict__ b_,
                                                 const float* __restrict__ g_,
                                                 const float* __restrict__ be_,
                                                 const float* __restrict__ m_,
                                                 const float* __restrict__ v_,
                                                 __half* __restrict__ out, int N) {
  __shared__ float4 Wsh[64];  // 32x16 fp16 = 1 KB
  if (threadIdx.x < 64) Wsh[threadIdx.x] = reinterpret_cast<const float4*>(Wp)[threadIdx.x];
  __syncthreads();

  int lane = threadIdx.x & 63;
  int wv = threadIdx.x >> 6;
  int quad = lane >> 4;
  int m = lane & 15;
  int rowBase = blockIdx.x * 64 + wv * 16;
  int node = rowBase + m;
  bool valid = node < N;
  int rd = valid ? node : N;
  int e0 = valid ? rowptr[node] : 0;
  int e1 = valid ? rowend[node] : 0;
  const float4* in16 = reinterpret_cast<const float4*>(hin);

  float acc[8];
  {
    F4H8 u;
    u.f4 = in16[(size_t)rd * 4 + quad];
#pragma unroll
    for (int i = 0; i < 4; ++i) {
      float2 t2 = __half22float2(u.h2[i]);
      acc[2 * i] = t2.x;
      acc[2 * i + 1] = t2.y;
    }
  }
  for (int e = e0; e < e1; e += 4) {
    int4 c = *reinterpret_cast<const int4*>(colidx + e);
    F4H8 u0, u1, u2, u3;
    u0.f4 = in16[(size_t)c.x * 4 + quad];
    u1.f4 = in16[(size_t)c.y * 4 + quad];
    u2.f4 = in16[(size_t)c.z * 4 + quad];
    u3.f4 = in16[(size_t)c.w * 4 + quad];
#pragma unroll
    for (int i = 0; i < 4; ++i) {
      float2 a = __half22float2(u0.h2[i]), b = __half22float2(u1.h2[i]);
      float2 cc = __half22float2(u2.h2[i]), d = __half22float2(u3.h2[i]);
      acc[2 * i] += (a.x + b.x) + (cc.x + d.x);
      acc[2 * i + 1] += (a.y + b.y) + (cc.y + d.y);
    }
  }
  float dvn = valid ? dinv[node] : 0.f;
  half8 afr;
#pragma unroll
  for (int j = 0; j < 8; ++j) {
    int f = quad * 8 + j;
    float sc = g_[f] * rsqrtf(v_[f] + BEPS);
    float val = fmaxf((acc[j] * dvn + b_[f] - m_[f]) * sc + be_[f], 0.f);
    afr[j] = (_Float16)val;
  }
  floatx4 c0 = (floatx4){0.f, 0.f, 0.f, 0.f};
  union { float4 f4; half8 h8; } ub;
  ub.f4 = Wsh[lane];
  c0 = __builtin_amdgcn_mfma_f32_16x16x32_f16(afr, ub.h8, c0, 0, 0, 0);
  int r0 = rowBase + quad * 4;
#pragma unroll
  for (int reg = 0; reg < 4; ++reg) {
    int r = r0 + reg;
    float dv = (r < N) ? dinv[r] : 0.f;
    out[(size_t)r * 16 + m] = __float2half(c0[reg] * dv);
  }
}

// ================= Standalone aggregation (agg1 MODE2, final MODE0) ==========
template <int F, int MODE, typename TO>
__global__ __launch_bounds__(TPB) void k_agg(const __half* __restrict__ in,
                                             const int* __restrict__ rowptr,
                                             const int* __restrict__ rowend,
                                             const int* __restrict__ colidx,
                                             const float* __restrict__ dinv,
                                             const float* __restrict__ bias,
                                             const float* __restrict__ g,
                                             const float* __restrict__ be,
                                             const float* __restrict__ m,
                                             const float* __restrict__ v,
                                             TO* __restrict__ out, int N) {
  constexpr int V = F / 8;
  constexpr int NPB = TPB / V;
  int node = blockIdx.x * NPB + (int)(threadIdx.x / V);
  int lane = threadIdx.x % V;
  if (node >= N) return;
  const float4* in16 = reinterpret_cast<const float4*>(in);
  const size_t rs = F / 8;
  float acc[8];
  {
    F4H8 u;
    u.f4 = in16[(size_t)node * rs + lane];
#pragma unroll
    for (int i = 0; i < 4; ++i) {
      float2 t2 = __half22float2(u.h2[i]);
      acc[2 * i] = t2.x;
      acc[2 * i + 1] = t2.y;
    }
  }
  int e0 = rowptr[node], e1 = rowend[node];
  int e = e0;
  for (; e + 8 <= e1; e += 8) {
    int4 c0 = *reinterpret_cast<const int4*>(colidx + e);
    int4 c1 = *reinterpret_cast<const int4*>(colidx + e + 4);
    F4H8 u[8];
    u[0].f4 = in16[(size_t)c0.x * rs + lane];
    u[1].f4 = in16[(size_t)c0.y * rs + lane];
    u[2].f4 = in16[(size_t)c0.z * rs + lane];
    u[3].f4 = in16[(size_t)c0.w * rs + lane];
    u[4].f4 = in16[(size_t)c1.x * rs + lane];
    u[5].f4 = in16[(size_t)c1.y * rs + lane];
    u[6].f4 = in16[(size_t)c1.z * rs + lane];
    u[7].f4 = in16[(size_t)c1.w * rs + lane];
#pragma unroll
    for (int q = 0; q < 8; ++q) {
#pragma unroll
      for (int i = 0; i < 4; ++i) {
        float2 t2 = __half22float2(u[q].h2[i]);
        acc[2 * i] += t2.x;
        acc[2 * i + 1] += t2.y;
      }
    }
  }
  float dv = dinv[node];
#pragma unroll
  for (int i = 0; i < 8; ++i) acc[i] *= dv;
  if (MODE == 0) {
    float4 ba = reinterpret_cast<const float4*>(bias)[lane * 2];
    float4 bb = reinterpret_cast<const float4*>(bias)[lane * 2 + 1];
    acc[0] += ba.x; acc[1] += ba.y; acc[2] += ba.z; acc[3] += ba.w;
    acc[4] += bb.x; acc[5] += bb.y; acc[6] += bb.z; acc[7] += bb.w;
  } else if (MODE == 1 || MODE == 2) {
    const float4* B = reinterpret_cast<const float4*>(bias);
    const float4* G = reinterpret_cast<const float4*>(g);
    const float4* Be = reinterpret_cast<const float4*>(be);
    const float4* M = reinterpret_cast<const float4*>(m);
    const float4* Vv = reinterpret_cast<const float4*>(v);
#pragma unroll
    for (int h = 0; h < 2; ++h) {
      float4 b4 = B[lane * 2 + h], g4 = G[lane * 2 + h], e4 = Be[lane * 2 + h];
      float4 m4 = M[lane * 2 + h], v4 = Vv[lane * 2 + h];
      float* a = acc + 4 * h;
      a[0] = fmaxf((a[0] + b4.x - m4.x) * (g4.x * rsqrtf(v4.x + BEPS)) + e4.x, 0.f);
      a[1] = fmaxf((a[1] + b4.y - m4.y) * (g4.y * rsqrtf(v4.y + BEPS)) + e4.y, 0.f);
      a[2] = fmaxf((a[2] + b4.z - m4.z) * (g4.z * rsqrtf(v4.z + BEPS)) + e4.z, 0.f);
      a[3] = fmaxf((a[3] + b4.w - m4.w) * (g4.w * rsqrtf(v4.w + BEPS)) + e4.w, 0.f);
    }
    if (MODE == 2) {
#pragma unroll
      for (int i = 0; i < 8; ++i) acc[i] *= dv;
    }
  }
  if constexpr (sizeof(TO) == 2) {
    F4H8 u;
#pragma unroll
    for (int i = 0; i < 4; ++i) u.h2[i] = __floats2half2_rn(acc[2 * i], acc[2 * i + 1]);
    reinterpret_cast<float4*>(out)[(size_t)node * rs + lane] = u.f4;
  } else {
    float4 o0 = {acc[0], acc[1], acc[2], acc[3]};
    float4 o1 = {acc[4], acc[5], acc[6], acc[7]};
    float4* op = reinterpret_cast<float4*>((float*)out + (size_t)node * F + lane * 8);
    op[0] = o0;
    op[1] = o1;
  }
}

// ================= launch =================

extern "C" void kernel_launch(void* const* d_in, const int* in_sizes, int n_in,
                              void* d_out, int out_size, void* d_ws, size_t ws_size,
                              hipStream_t stream) {
  const float* x = (const float*)d_in[0];
  const int* ei = (const int*)d_in[1];
  const int N = in_sizes[0] / 128;
  const int E = in_sizes[1] / 2;
  const int* src = ei;
  const int* dst = ei + E;

  const float* w1 = (const float*)d_in[2];  const float* b1 = (const float*)d_in[3];
  const float* w2 = (const float*)d_in[4];  const float* b2 = (const float*)d_in[5];
  const float* w3 = (const float*)d_in[6];  const float* b3 = (const float*)d_in[7];
  const float* w4 = (const float*)d_in[8];  const float* b4 = (const float*)d_in[9];
  const float* w5 = (const float*)d_in[10]; const float* b5 = (const float*)d_in[11];
  const float* g1 = (const float*)d_in[12]; const float* be1 = (const float*)d_in[13];
  const float* m1 = (const float*)d_in[14]; const float* v1 = (const float*)d_in[15];
  const float* g2 = (const float*)d_in[16]; const float* be2 = (const float*)d_in[17];
  const float* m2 = (const float*)d_in[18]; const float* v2 = (const float*)d_in[19];
  const float* g3 = (const float*)d_in[20]; const float* be3 = (const float*)d_in[21];
  const float* m3 = (const float*)d_in[22]; const float* v3 = (const float*)d_in[23];
  const float* g4 = (const float*)d_in[24]; const float* be4 = (const float*)d_in[25];
  const float* m4 = (const float*)d_in[26]; const float* v4 = (const float*)d_in[27];
  float* out = (float*)d_out;

  char* ws = (char*)d_ws;
  size_t off = 0;
  auto alloc = [&](size_t bytes) -> void* {
    void* p = ws + off;
    off += (bytes + 255) & ~(size_t)255;
    return p;
  };
  const int K = (N + BK_NODES - 1) >> BK_SHIFT;  // 391 for N=100000
  float*        dinv   = (float*)alloc((size_t)N * 4);
  int*          rowptr = (int*)alloc((size_t)N * 4);
  int*          rowend = (int*)alloc((size_t)N * 4);
  int*          colidx = (int*)alloc(((size_t)E + (size_t)(K + 1) * BK_SLACK) * 4);
  unsigned int* pairs  = (unsigned int*)alloc((size_t)E * 4);
  int*          histG  = (int*)alloc((size_t)KMAX * G_SC * 4);
  int*          offs   = (int*)alloc((size_t)KMAX * G_SC * 4);
  int*          btot   = (int*)alloc(KMAX * 4);
  int*          bbase  = (int*)alloc((KMAX + 1) * 4);
  _Float16*     wp1    = (_Float16*)alloc(128 * 64 * 2);
  _Float16*     wp2    = (_Float16*)alloc(64 * 128 * 2);
  _Float16*     wp3    = (_Float16*)alloc(128 * 64 * 2);
  _Float16*     wp4    = (_Float16*)alloc(64 * 32 * 2);
  _Float16*     wp5    = (_Float16*)alloc(32 * 16 * 2);
  __half*       bufA   = (__half*)alloc((size_t)(N + 64) * 128 * 2);
  __half*       bufB   = (__half*)alloc((size_t)(N + 64) * 128 * 2);
  (void)ws_size; (void)n_in; (void)out_size;

  const int chunk = (((E + G_SC - 1) / G_SC) + 3) & ~3;  // 4-aligned for int4 reads

  // CSR build (padded colidx; vectorized edge streams)
  k_zero_int<<<2, TPB, 0, stream>>>(btot, KMAX);
  k_hist<<<G_SC, TPB, 0, stream>>>(dst, histG, btot, E, K, chunk);
  k_bbase<<<1, KMAX, 0, stream>>>(btot, bbase, K);
  k_offs<<<K, G_SC, 0, stream>>>(histG, bbase, offs);
  k_scatter<<<G_SC, TPB, 0, stream>>>(src, dst, offs, pairs, E, K, chunk);
  k_bucket_sort<<<K, TPB, 0, stream>>>(pairs, bbase, rowptr, rowend, colidx, dinv, N, E);

  // pack weights + zero bufA's F=64 sentinel row
  k_packAll<<<(27144 + TPB - 1) / TPB, TPB, 0, stream>>>(w1, wp1, w2, wp2, w3, wp3, w4, wp4, w5, wp5, bufA, N);

  int gRow = (N + 63) / 64;
  // L1: MFMA GEMM(128->64)*dinv -> bufB; AGG(64)+BN1+ReLU emit *dinv -> bufA
  k_mgemm<128, 64, 0, true><<<gRow, TPB, 0, stream>>>(x, wp1, dinv, nullptr, nullptr, nullptr, nullptr, nullptr, bufB, N);
  k_agg<64, 2, __half><<<(N + 31) / 32, TPB, 0, stream>>>(bufB, rowptr, rowend, colidx, dinv, b1, g1, be1, m1, v1, bufA, N);
  // L2+L3 head fused: gather(agg) -> 64->128 BN2/ReLU -> 128->64 *dinv -> bufB
  k_aggemm23<<<gRow, TPB, 0, stream>>>(bufA, rowptr, rowend, colidx, wp2, wp3, dinv, b2, g2, be2, m2, v2, bufB, N);
  // L3 agg + L4 gemm fused: gather+BN3/ReLU -> 64->32 *dinv -> bufA
  k_aggemm64<32><<<gRow, TPB, 0, stream>>>(bufB, rowptr, rowend, colidx, wp4, dinv, b3, g3, be3, m3, v3, bufA, N);
  // L4 agg + L5 gemm fused: gather+BN4/ReLU -> 32->16 *dinv -> bufB
  k_aggemm5<<<gRow, TPB, 0, stream>>>(bufA, rowptr, rowend, colidx, wp5, dinv, b4, g4, be4, m4, v4, bufB, N);
  // final agg(16) + bias -> f32 out
  k_agg<16, 0, float><<<(N + 127) / 128, TPB, 0, stream>>>(bufB, rowptr, rowend, colidx, dinv, b5, nullptr, nullptr, nullptr, nullptr, out, N);
}

// Round 10
// 357.112 us; speedup vs baseline: 1.0202x; 1.0202x over previous
//
#include <hip/hip_runtime.h>
#include <hip/hip_fp16.h>

#define BEPS 1e-5f
static constexpr int TPB = 256;
static constexpr int G_SC = 512;      // scatter workgroups
static constexpr int BK_SHIFT = 8;    // bucket = 256-node range
static constexpr int BK_NODES = 256;
static constexpr int KMAX = 512;      // max buckets (N <= 131072)
static constexpr int BK_SLACK = 2048; // per-bucket colidx padding slack

union F4H8 { float4 f4; __half2 h2[4]; };  // 16B = 8 halfs

typedef _Float16 half8 __attribute__((ext_vector_type(8)));
typedef float floatx4 __attribute__((ext_vector_type(4)));

// ================= CSR build: two-level bucket counting sort =================

__global__ __launch_bounds__(TPB) void k_zero_int(int* __restrict__ p, int n) {
  int i = blockIdx.x * TPB + threadIdx.x;
  if (i < n) p[i] = 0;
}

__global__ __launch_bounds__(TPB) void k_hist(const int* __restrict__ dst,
                                              int* __restrict__ histG,
                                              int* __restrict__ btot,
                                              int E, int K, int chunk) {
  __shared__ int lh[KMAX];
  int g = blockIdx.x, t = threadIdx.x;
  for (int i = t; i < KMAX; i += TPB) lh[i] = 0;
  __syncthreads();
  int e0 = g * chunk, e1 = min(E, e0 + chunk);
  for (int e = e0 + t * 4; e < e1; e += TPB * 4) {
    if (e + 4 <= e1) {
      int4 d4 = *reinterpret_cast<const int4*>(dst + e);
      atomicAdd(&lh[d4.x >> BK_SHIFT], 1);
      atomicAdd(&lh[d4.y >> BK_SHIFT], 1);
      atomicAdd(&lh[d4.z >> BK_SHIFT], 1);
      atomicAdd(&lh[d4.w >> BK_SHIFT], 1);
    } else {
      for (int q = e; q < e1; ++q) atomicAdd(&lh[dst[q] >> BK_SHIFT], 1);
    }
  }
  __syncthreads();
  for (int i = t; i < K; i += TPB) {
    histG[i * G_SC + g] = lh[i];
    atomicAdd(&btot[i], lh[i]);
  }
}

__global__ __launch_bounds__(KMAX) void k_bbase(const int* __restrict__ btot,
                                                int* __restrict__ bbase, int K) {
  __shared__ int sh[KMAX];
  int t = threadIdx.x;
  int v = (t < K) ? btot[t] : 0;
  sh[t] = v;
  __syncthreads();
  for (int s = 1; s < KMAX; s <<= 1) {
    int x = sh[t];
    int y = (t >= s) ? sh[t - s] : 0;
    __syncthreads();
    sh[t] = x + y;
    __syncthreads();
  }
  if (t < K) bbase[t] = sh[t] - v;
  if (t == 0) bbase[K] = sh[K - 1];
}

__global__ __launch_bounds__(G_SC) void k_offs(const int* __restrict__ histG,
                                               const int* __restrict__ bbase,
                                               int* __restrict__ offs) {
  __shared__ int sh[G_SC];
  int b = blockIdx.x, t = threadIdx.x;
  int v = histG[b * G_SC + t];
  sh[t] = v;
  __syncthreads();
  for (int s = 1; s < G_SC; s <<= 1) {
    int x = sh[t];
    int y = (t >= s) ? sh[t - s] : 0;
    __syncthreads();
    sh[t] = x + y;
    __syncthreads();
  }
  offs[b * G_SC + t] = bbase[b] + sh[t] - v;
}

__global__ __launch_bounds__(TPB) void k_scatter(const int* __restrict__ src,
                                                 const int* __restrict__ dst,
                                                 const int* __restrict__ offs,
                                                 unsigned int* __restrict__ pairs,
                                                 int E, int K, int chunk) {
  __shared__ int cur[KMAX];
  int g = blockIdx.x, t = threadIdx.x;
  for (int i = t; i < K; i += TPB) cur[i] = offs[i * G_SC + g];
  __syncthreads();
  int e0 = g * chunk, e1 = min(E, e0 + chunk);
  for (int e = e0 + t * 4; e < e1; e += TPB * 4) {
    if (e + 4 <= e1) {
      int4 d4 = *reinterpret_cast<const int4*>(dst + e);
      int4 s4 = *reinterpret_cast<const int4*>(src + e);
      int p0 = atomicAdd(&cur[d4.x >> BK_SHIFT], 1);
      pairs[p0] = (unsigned int)s4.x | ((unsigned int)(d4.x & (BK_NODES - 1)) << 20);
      int p1 = atomicAdd(&cur[d4.y >> BK_SHIFT], 1);
      pairs[p1] = (unsigned int)s4.y | ((unsigned int)(d4.y & (BK_NODES - 1)) << 20);
      int p2 = atomicAdd(&cur[d4.z >> BK_SHIFT], 1);
      pairs[p2] = (unsigned int)s4.z | ((unsigned int)(d4.z & (BK_NODES - 1)) << 20);
      int p3 = atomicAdd(&cur[d4.w >> BK_SHIFT], 1);
      pairs[p3] = (unsigned int)s4.w | ((unsigned int)(d4.w & (BK_NODES - 1)) << 20);
    } else {
      for (int q = e; q < e1; ++q) {
        int d = dst[q];
        int pos = atomicAdd(&cur[d >> BK_SHIFT], 1);
        pairs[pos] = (unsigned int)src[q] | ((unsigned int)(d & (BK_NODES - 1)) << 20);
      }
    }
  }
}

// per-bucket LDS counting sort -> PADDED colidx (lists padded to multiple of 8
// with sentinel N -> zero row; 8-aligned starts; tail-free agg loops).
__global__ __launch_bounds__(TPB) void k_bucket_sort(const unsigned int* __restrict__ pairs,
                                                     const int* __restrict__ bbase,
                                                     int* __restrict__ rowptr,
                                                     int* __restrict__ rowend,
                                                     int* __restrict__ colidx,
                                                     float* __restrict__ dinv,
                                                     int N, int E) {
  __shared__ int cur[BK_NODES];
  __shared__ int sh[BK_NODES];
  int b = blockIdx.x, t = threadIdx.x;
  int base = bbase[b], end = bbase[b + 1];
  int n0 = b << BK_SHIFT;
  int nNodes = min(BK_NODES, N - n0);
  cur[t] = 0;
  __syncthreads();
  for (int e = base + t; e < end; e += TPB) atomicAdd(&cur[pairs[e] >> 20], 1);
  __syncthreads();
  int v = cur[t];                 // raw degree
  int pd = (v + 7) & ~7;          // padded degree
  sh[t] = pd;
  __syncthreads();
  for (int s = 1; s < TPB; s <<= 1) {
    int x = sh[t];
    int y = (t >= s) ? sh[t - s] : 0;
    __syncthreads();
    sh[t] = x + y;
    __syncthreads();
  }
  int Bb = (base + b * BK_SLACK + 7) & ~7;
  int start = Bb + (sh[t] - pd);
  if (t < nNodes) {
    rowptr[n0 + t] = start;
    rowend[n0 + t] = start + pd;
    dinv[n0 + t] = rsqrtf((float)(v + 1));
    for (int i = start + v; i < start + pd; ++i) colidx[i] = N;  // pads -> zero row
  }
  __syncthreads();
  cur[t] = start;
  __syncthreads();
  for (int e = base + t; e < end; e += TPB) {
    unsigned int p = pairs[e];
    int pos = atomicAdd(&cur[p >> 20], 1);
    colidx[pos] = (int)(p & 0xFFFFFu);
  }
}

// ================= W pack (all 5 weights) + bufA zero-row init =================
__device__ inline void packone(const float* __restrict__ W, _Float16* __restrict__ Wp,
                               int i, int FO) {
  int j = i & 7, lane = (i >> 3) & 63, tile = i >> 9;
  int nct = FO >> 4, ct = tile % nct, kch = tile / nct;
  int k = kch * 32 + ((lane >> 4) << 3) + j;
  int n = (ct << 4) + (lane & 15);
  Wp[i] = (_Float16)W[k * FO + n];
}

__global__ __launch_bounds__(TPB) void k_packAll(const float* w1, _Float16* p1,
                                                 const float* w2, _Float16* p2,
                                                 const float* w3, _Float16* p3,
                                                 const float* w4, _Float16* p4,
                                                 const float* w5, _Float16* p5,
                                                 __half* bufA, int N) {
  int i = blockIdx.x * TPB + threadIdx.x;
  if (i < 8192) packone(w1, p1, i, 64);
  else if (i < 16384) packone(w2, p2, i - 8192, 128);
  else if (i < 24576) packone(w3, p3, i - 16384, 64);
  else if (i < 26624) packone(w4, p4, i - 24576, 32);
  else if (i < 27136) packone(w5, p5, i - 26624, 16);
  else if (i < 27144) {  // zero bufA's F=64 sentinel row N
    float4 z = {0.f, 0.f, 0.f, 0.f};
    reinterpret_cast<float4*>(bufA + (size_t)64 * N)[i - 27136] = z;
  }
}

// ================= L1 MFMA GEMM, LDS-staged x (128 -> 64, *dinv) =============
// R10: old version's A-loads were 32B strided reads from 16 rows 512B apart
// (16-line scatter per instr). Stage the 64x128 f32 tile via fully-coalesced
// dwordx4 streaming + fp32->fp16 once; fragment reads from LDS (pitch 136).
__global__ __launch_bounds__(TPB) void k_mgemm1(const float* __restrict__ x,
                                                const _Float16* __restrict__ Wp,
                                                const float* __restrict__ dinv,
                                                __half* __restrict__ out, int N) {
  __shared__ float4 Wsh[4 * 4 * 64];       // 128x64 fp16 = 16 KB
  __shared__ _Float16 xs[64 * 136];        // 17.4 KB staged fp16 x-tile
  for (int i = threadIdx.x; i < 1024; i += TPB)
    Wsh[i] = reinterpret_cast<const float4*>(Wp)[i];
  int rowBase = blockIdx.x * 64;
  for (int i = threadIdx.x; i < 2048; i += TPB) {  // 64 rows x 32 float4, coalesced
    int r = i >> 5, c4 = i & 31;
    int gr = rowBase + r;
    float4 f = {0.f, 0.f, 0.f, 0.f};
    if (gr < N) f = reinterpret_cast<const float4*>(x)[(size_t)gr * 32 + c4];
    _Float16* p = &xs[r * 136 + c4 * 4];
    p[0] = (_Float16)f.x; p[1] = (_Float16)f.y; p[2] = (_Float16)f.z; p[3] = (_Float16)f.w;
  }
  __syncthreads();

  int lane = threadIdx.x & 63;
  int wv = threadIdx.x >> 6;
  int quad = lane >> 4;
  int m = lane & 15;
  int lrow = wv * 16 + m;  // block-local row

  floatx4 acc[4];
#pragma unroll
  for (int ct = 0; ct < 4; ++ct) acc[ct] = (floatx4){0.f, 0.f, 0.f, 0.f};
#pragma unroll
  for (int kch = 0; kch < 4; ++kch) {
    half8 a = *reinterpret_cast<const half8*>(&xs[lrow * 136 + kch * 32 + quad * 8]);
#pragma unroll
    for (int ct = 0; ct < 4; ++ct) {
      union { float4 f4; half8 h8; } ub;
      ub.f4 = Wsh[(kch * 4 + ct) * 64 + lane];
      acc[ct] = __builtin_amdgcn_mfma_f32_16x16x32_f16(a, ub.h8, acc[ct], 0, 0, 0);
    }
  }
  int r0 = rowBase + wv * 16 + quad * 4;
  float dv[4];
#pragma unroll
  for (int reg = 0; reg < 4; ++reg) dv[reg] = (r0 + reg < N) ? dinv[r0 + reg] : 0.f;
#pragma unroll
  for (int ct = 0; ct < 4; ++ct) {
    int col = ct * 16 + m;
#pragma unroll
    for (int reg = 0; reg < 4; ++reg) {
      int r = r0 + reg;
      out[(size_t)r * 64 + col] = __float2half(acc[ct][reg] * dv[reg]);
    }
  }
}

// ================= MFMA GEMM (L4: 64->32, *dinv; rows>=N -> zero) ============
template <int FI, int FO>
__global__ __launch_bounds__(TPB) void k_mgemm(const __half* __restrict__ hin,
                                               const _Float16* __restrict__ Wp,
                                               const float* __restrict__ dinv,
                                               __half* __restrict__ out, int N) {
  constexpr int NCT = FO / 16;
  constexpr int NKC = FI / 32;
  __shared__ float4 Wsh[NKC * NCT * 64];
  for (int i = threadIdx.x; i < NKC * NCT * 64; i += TPB)
    Wsh[i] = reinterpret_cast<const float4*>(Wp)[i];
  __syncthreads();

  int lane = threadIdx.x & 63;
  int wv = threadIdx.x >> 6;
  int quad = lane >> 4;
  int rowBase = blockIdx.x * 64 + wv * 16;
  int rA = min(rowBase + (lane & 15), N - 1);

  floatx4 acc[NCT];
#pragma unroll
  for (int ct = 0; ct < NCT; ++ct) acc[ct] = (floatx4){0.f, 0.f, 0.f, 0.f};
#pragma unroll
  for (int kch = 0; kch < NKC; ++kch) {
    union { float4 f4; half8 h8; } ua;
    ua.f4 = reinterpret_cast<const float4*>(hin)[((size_t)rA * FI + kch * 32 + quad * 8) >> 3];
#pragma unroll
    for (int ct = 0; ct < NCT; ++ct) {
      union { float4 f4; half8 h8; } ub;
      ub.f4 = Wsh[(kch * NCT + ct) * 64 + lane];
      acc[ct] = __builtin_amdgcn_mfma_f32_16x16x32_f16(ua.h8, ub.h8, acc[ct], 0, 0, 0);
    }
  }
  int r0 = rowBase + quad * 4;
  float dv[4];
#pragma unroll
  for (int reg = 0; reg < 4; ++reg) dv[reg] = (r0 + reg < N) ? dinv[r0 + reg] : 0.f;
#pragma unroll
  for (int ct = 0; ct < NCT; ++ct) {
    int col = ct * 16 + (lane & 15);
#pragma unroll
    for (int reg = 0; reg < 4; ++reg) {
      int r = r0 + reg;
      out[(size_t)r * FO + col] = __float2half(acc[ct][reg] * dv[reg]);
    }
  }
}

// ========== Fused L2 GEMM chain: h3 = (relu(bn(h2@W2)) @ W3) * dinv ==========
__global__ __launch_bounds__(TPB) void k_mgemm23(const __half* __restrict__ hin,
                                                 const _Float16* __restrict__ W2p,
                                                 const _Float16* __restrict__ W3p,
                                                 const float* __restrict__ dinv,
                                                 const float* __restrict__ b2,
                                                 const float* __restrict__ g2,
                                                 const float* __restrict__ be2,
                                                 const float* __restrict__ m2,
                                                 const float* __restrict__ v2,
                                                 __half* __restrict__ out, int N) {
  __shared__ float4 W2s[2 * 8 * 64];       // 16 KB
  __shared__ float4 W3s[4 * 4 * 64];       // 16 KB
  __shared__ _Float16 tr[4 * 16 * 136];    // 17 KB
  for (int i = threadIdx.x; i < 1024; i += TPB) W2s[i] = reinterpret_cast<const float4*>(W2p)[i];
  for (int i = threadIdx.x; i < 1024; i += TPB) W3s[i] = reinterpret_cast<const float4*>(W3p)[i];
  __syncthreads();

  int lane = threadIdx.x & 63;
  int wv = threadIdx.x >> 6;
  int quad = lane >> 4;
  int m = lane & 15;
  int rowBase = blockIdx.x * 64 + wv * 16;
  int rA = min(rowBase + m, N - 1);

  floatx4 acc1[8];
#pragma unroll
  for (int ct = 0; ct < 8; ++ct) acc1[ct] = (floatx4){0.f, 0.f, 0.f, 0.f};
#pragma unroll
  for (int kch = 0; kch < 2; ++kch) {
    union { float4 f4; half8 h8; } ua;
    ua.f4 = reinterpret_cast<const float4*>(hin)[((size_t)rA * 64 + kch * 32 + quad * 8) >> 3];
#pragma unroll
    for (int ct = 0; ct < 8; ++ct) {
      union { float4 f4; half8 h8; } ub;
      ub.f4 = W2s[(kch * 8 + ct) * 64 + lane];
      acc1[ct] = __builtin_amdgcn_mfma_f32_16x16x32_f16(ua.h8, ub.h8, acc1[ct], 0, 0, 0);
    }
  }
  _Float16* mytr = tr + wv * 16 * 136;
#pragma unroll
  for (int ct = 0; ct < 8; ++ct) {
    int col = ct * 16 + m;
    float sc = g2[col] * rsqrtf(v2[col] + BEPS);
    float bb = b2[col] - m2[col];
    float ee = be2[col];
#pragma unroll
    for (int reg = 0; reg < 4; ++reg) {
      int r = quad * 4 + reg;
      mytr[r * 136 + col] = (_Float16)fmaxf((acc1[ct][reg] + bb) * sc + ee, 0.f);
    }
  }
  floatx4 acc2[4];
#pragma unroll
  for (int ct = 0; ct < 4; ++ct) acc2[ct] = (floatx4){0.f, 0.f, 0.f, 0.f};
#pragma unroll
  for (int kch = 0; kch < 4; ++kch) {
    half8 a2 = *reinterpret_cast<const half8*>(&mytr[m * 136 + kch * 32 + quad * 8]);
#pragma unroll
    for (int ct = 0; ct < 4; ++ct) {
      union { float4 f4; half8 h8; } ub;
      ub.f4 = W3s[(kch * 4 + ct) * 64 + lane];
      acc2[ct] = __builtin_amdgcn_mfma_f32_16x16x32_f16(a2, ub.h8, acc2[ct], 0, 0, 0);
    }
  }
  int r0 = rowBase + quad * 4;
  float dv[4];
#pragma unroll
  for (int reg = 0; reg < 4; ++reg) dv[reg] = (r0 + reg < N) ? dinv[r0 + reg] : 0.f;
#pragma unroll
  for (int ct = 0; ct < 4; ++ct) {
    int col = ct * 16 + m;
#pragma unroll
    for (int reg = 0; reg < 4; ++reg) {
      int r = r0 + reg;
      out[(size_t)r * 64 + col] = __float2half(acc2[ct][reg] * dv[reg]);
    }
  }
}

// ====== Fused agg(BN4)+GEMM, FI=32 -> FO=16 (same wave shape as agg<32>) =====
__global__ __launch_bounds__(TPB) void k_aggemm5(const __half* __restrict__ hin,
                                                 const int* __restrict__ rowptr,
                                                 const int* __restrict__ rowend,
                                                 const int* __restrict__ colidx,
                                                 const _Float16* __restrict__ Wp,
                                                 const float* __restrict__ dinv,
                                                 const float* __restrict__ b_,
                                                 const float* __restrict__ g_,
                                                 const float* __restrict__ be_,
                                                 const float* __restrict__ m_,
                                                 const float* __restrict__ v_,
                                                 __half* __restrict__ out, int N) {
  __shared__ float4 Wsh[64];  // 32x16 fp16 = 1 KB
  if (threadIdx.x < 64) Wsh[threadIdx.x] = reinterpret_cast<const float4*>(Wp)[threadIdx.x];
  __syncthreads();

  int lane = threadIdx.x & 63;
  int wv = threadIdx.x >> 6;
  int quad = lane >> 4;
  int m = lane & 15;
  int rowBase = blockIdx.x * 64 + wv * 16;
  int node = rowBase + m;
  bool valid = node < N;
  int rd = valid ? node : N;
  int e0 = valid ? rowptr[node] : 0;
  int e1 = valid ? rowend[node] : 0;
  const float4* in16 = reinterpret_cast<const float4*>(hin);

  float acc[8];
  {
    F4H8 u;
    u.f4 = in16[(size_t)rd * 4 + quad];
#pragma unroll
    for (int i = 0; i < 4; ++i) {
      float2 t2 = __half22float2(u.h2[i]);
      acc[2 * i] = t2.x;
      acc[2 * i + 1] = t2.y;
    }
  }
  for (int e = e0; e < e1; e += 4) {
    int4 c = *reinterpret_cast<const int4*>(colidx + e);
    F4H8 u0, u1, u2, u3;
    u0.f4 = in16[(size_t)c.x * 4 + quad];
    u1.f4 = in16[(size_t)c.y * 4 + quad];
    u2.f4 = in16[(size_t)c.z * 4 + quad];
    u3.f4 = in16[(size_t)c.w * 4 + quad];
#pragma unroll
    for (int i = 0; i < 4; ++i) {
      float2 a = __half22float2(u0.h2[i]), b = __half22float2(u1.h2[i]);
      float2 cc = __half22float2(u2.h2[i]), d = __half22float2(u3.h2[i]);
      acc[2 * i] += (a.x + b.x) + (cc.x + d.x);
      acc[2 * i + 1] += (a.y + b.y) + (cc.y + d.y);
    }
  }
  float dvn = valid ? dinv[node] : 0.f;
  half8 afr;
#pragma unroll
  for (int j = 0; j < 8; ++j) {
    int f = quad * 8 + j;
    float sc = g_[f] * rsqrtf(v_[f] + BEPS);
    float val = fmaxf((acc[j] * dvn + b_[f] - m_[f]) * sc + be_[f], 0.f);
    afr[j] = (_Float16)val;
  }
  floatx4 c0 = (floatx4){0.f, 0.f, 0.f, 0.f};
  union { float4 f4; half8 h8; } ub;
  ub.f4 = Wsh[lane];
  c0 = __builtin_amdgcn_mfma_f32_16x16x32_f16(afr, ub.h8, c0, 0, 0, 0);
  int r0 = rowBase + quad * 4;
#pragma unroll
  for (int reg = 0; reg < 4; ++reg) {
    int r = r0 + reg;
    float dv = (r < N) ? dinv[r] : 0.f;
    out[(size_t)r * 16 + m] = __float2half(c0[reg] * dv);
  }
}

// ================= Standalone aggregation (fp16 in, f32 accumulate) ==========
// Padded CSR; 16 gathers in flight + one 8-chunk tail; 8 lanes cover a full
// 128B row per gather instruction (the efficient wave shape — R9 post-mortem).
// MODE 0: val+bias (TO=float, final)  MODE 1: relu(bn(val+bias))
// MODE 2: relu(bn(val+bias))*dinv     MODE 3: val (pre-GEMM agg)
template <int F, int MODE, typename TO>
__global__ __launch_bounds__(TPB) void k_agg(const __half* __restrict__ in,
                                             const int* __restrict__ rowptr,
                                             const int* __restrict__ rowend,
                                             const int* __restrict__ colidx,
                                             const float* __restrict__ dinv,
                                             const float* __restrict__ bias,
                                             const float* __restrict__ g,
                                             const float* __restrict__ be,
                                             const float* __restrict__ m,
                                             const float* __restrict__ v,
                                             TO* __restrict__ out, int N) {
  constexpr int V = F / 8;
  constexpr int NPB = TPB / V;
  int node = blockIdx.x * NPB + (int)(threadIdx.x / V);
  int lane = threadIdx.x % V;
  if (node >= N) return;
  const float4* in16 = reinterpret_cast<const float4*>(in);
  const size_t rs = F / 8;
  float acc[8];
  {
    F4H8 u;
    u.f4 = in16[(size_t)node * rs + lane];
#pragma unroll
    for (int i = 0; i < 4; ++i) {
      float2 t2 = __half22float2(u.h2[i]);
      acc[2 * i] = t2.x;
      acc[2 * i + 1] = t2.y;
    }
  }
  int e0 = rowptr[node], e1 = rowend[node];
  int e = e0;
  for (; e + 16 <= e1; e += 16) {
    int4 c0 = *reinterpret_cast<const int4*>(colidx + e);
    int4 c1 = *reinterpret_cast<const int4*>(colidx + e + 4);
    int4 c2 = *reinterpret_cast<const int4*>(colidx + e + 8);
    int4 c3 = *reinterpret_cast<const int4*>(colidx + e + 12);
    F4H8 u[16];
    u[0].f4  = in16[(size_t)c0.x * rs + lane];
    u[1].f4  = in16[(size_t)c0.y * rs + lane];
    u[2].f4  = in16[(size_t)c0.z * rs + lane];
    u[3].f4  = in16[(size_t)c0.w * rs + lane];
    u[4].f4  = in16[(size_t)c1.x * rs + lane];
    u[5].f4  = in16[(size_t)c1.y * rs + lane];
    u[6].f4  = in16[(size_t)c1.z * rs + lane];
    u[7].f4  = in16[(size_t)c1.w * rs + lane];
    u[8].f4  = in16[(size_t)c2.x * rs + lane];
    u[9].f4  = in16[(size_t)c2.y * rs + lane];
    u[10].f4 = in16[(size_t)c2.z * rs + lane];
    u[11].f4 = in16[(size_t)c2.w * rs + lane];
    u[12].f4 = in16[(size_t)c3.x * rs + lane];
    u[13].f4 = in16[(size_t)c3.y * rs + lane];
    u[14].f4 = in16[(size_t)c3.z * rs + lane];
    u[15].f4 = in16[(size_t)c3.w * rs + lane];
#pragma unroll
    for (int q = 0; q < 16; ++q) {
#pragma unroll
      for (int i = 0; i < 4; ++i) {
        float2 t2 = __half22float2(u[q].h2[i]);
        acc[2 * i] += t2.x;
        acc[2 * i + 1] += t2.y;
      }
    }
  }
  if (e < e1) {
    int4 c0 = *reinterpret_cast<const int4*>(colidx + e);
    int4 c1 = *reinterpret_cast<const int4*>(colidx + e + 4);
    F4H8 u[8];
    u[0].f4 = in16[(size_t)c0.x * rs + lane];
    u[1].f4 = in16[(size_t)c0.y * rs + lane];
    u[2].f4 = in16[(size_t)c0.z * rs + lane];
    u[3].f4 = in16[(size_t)c0.w * rs + lane];
    u[4].f4 = in16[(size_t)c1.x * rs + lane];
    u[5].f4 = in16[(size_t)c1.y * rs + lane];
    u[6].f4 = in16[(size_t)c1.z * rs + lane];
    u[7].f4 = in16[(size_t)c1.w * rs + lane];
#pragma unroll
    for (int q = 0; q < 8; ++q) {
#pragma unroll
      for (int i = 0; i < 4; ++i) {
        float2 t2 = __half22float2(u[q].h2[i]);
        acc[2 * i] += t2.x;
        acc[2 * i + 1] += t2.y;
      }
    }
  }
  float dv = dinv[node];
#pragma unroll
  for (int i = 0; i < 8; ++i) acc[i] *= dv;
  if (MODE == 0) {
    float4 ba = reinterpret_cast<const float4*>(bias)[lane * 2];
    float4 bb = reinterpret_cast<const float4*>(bias)[lane * 2 + 1];
    acc[0] += ba.x; acc[1] += ba.y; acc[2] += ba.z; acc[3] += ba.w;
    acc[4] += bb.x; acc[5] += bb.y; acc[6] += bb.z; acc[7] += bb.w;
  } else if (MODE == 1 || MODE == 2) {
    const float4* B = reinterpret_cast<const float4*>(bias);
    const float4* G = reinterpret_cast<const float4*>(g);
    const float4* Be = reinterpret_cast<const float4*>(be);
    const float4* M = reinterpret_cast<const float4*>(m);
    const float4* Vv = reinterpret_cast<const float4*>(v);
#pragma unroll
    for (int h = 0; h < 2; ++h) {
      float4 b4 = B[lane * 2 + h], g4 = G[lane * 2 + h], e4 = Be[lane * 2 + h];
      float4 m4 = M[lane * 2 + h], v4 = Vv[lane * 2 + h];
      float* a = acc + 4 * h;
      a[0] = fmaxf((a[0] + b4.x - m4.x) * (g4.x * rsqrtf(v4.x + BEPS)) + e4.x, 0.f);
      a[1] = fmaxf((a[1] + b4.y - m4.y) * (g4.y * rsqrtf(v4.y + BEPS)) + e4.y, 0.f);
      a[2] = fmaxf((a[2] + b4.z - m4.z) * (g4.z * rsqrtf(v4.z + BEPS)) + e4.z, 0.f);
      a[3] = fmaxf((a[3] + b4.w - m4.w) * (g4.w * rsqrtf(v4.w + BEPS)) + e4.w, 0.f);
    }
    if (MODE == 2) {
#pragma unroll
      for (int i = 0; i < 8; ++i) acc[i] *= dv;
    }
  }
  if constexpr (sizeof(TO) == 2) {
    F4H8 u;
#pragma unroll
    for (int i = 0; i < 4; ++i) u.h2[i] = __floats2half2_rn(acc[2 * i], acc[2 * i + 1]);
    reinterpret_cast<float4*>(out)[(size_t)node * rs + lane] = u.f4;
  } else {
    float4 o0 = {acc[0], acc[1], acc[2], acc[3]};
    float4 o1 = {acc[4], acc[5], acc[6], acc[7]};
    float4* op = reinterpret_cast<float4*>((float*)out + (size_t)node * F + lane * 8);
    op[0] = o0;
    op[1] = o1;
  }
}

// ================= launch =================

extern "C" void kernel_launch(void* const* d_in, const int* in_sizes, int n_in,
                              void* d_out, int out_size, void* d_ws, size_t ws_size,
                              hipStream_t stream) {
  const float* x = (const float*)d_in[0];
  const int* ei = (const int*)d_in[1];
  const int N = in_sizes[0] / 128;
  const int E = in_sizes[1] / 2;
  const int* src = ei;
  const int* dst = ei + E;

  const float* w1 = (const float*)d_in[2];  const float* b1 = (const float*)d_in[3];
  const float* w2 = (const float*)d_in[4];  const float* b2 = (const float*)d_in[5];
  const float* w3 = (const float*)d_in[6];  const float* b3 = (const float*)d_in[7];
  const float* w4 = (const float*)d_in[8];  const float* b4 = (const float*)d_in[9];
  const float* w5 = (const float*)d_in[10]; const float* b5 = (const float*)d_in[11];
  const float* g1 = (const float*)d_in[12]; const float* be1 = (const float*)d_in[13];
  const float* m1 = (const float*)d_in[14]; const float* v1 = (const float*)d_in[15];
  const float* g2 = (const float*)d_in[16]; const float* be2 = (const float*)d_in[17];
  const float* m2 = (const float*)d_in[18]; const float* v2 = (const float*)d_in[19];
  const float* g3 = (const float*)d_in[20]; const float* be3 = (const float*)d_in[21];
  const float* m3 = (const float*)d_in[22]; const float* v3 = (const float*)d_in[23];
  const float* g4 = (const float*)d_in[24]; const float* be4 = (const float*)d_in[25];
  const float* m4 = (const float*)d_in[26]; const float* v4 = (const float*)d_in[27];
  float* out = (float*)d_out;

  char* ws = (char*)d_ws;
  size_t off = 0;
  auto alloc = [&](size_t bytes) -> void* {
    void* p = ws + off;
    off += (bytes + 255) & ~(size_t)255;
    return p;
  };
  const int K = (N + BK_NODES - 1) >> BK_SHIFT;  // 391 for N=100000
  float*        dinv   = (float*)alloc((size_t)N * 4);
  int*          rowptr = (int*)alloc((size_t)N * 4);
  int*          rowend = (int*)alloc((size_t)N * 4);
  int*          colidx = (int*)alloc(((size_t)E + (size_t)(K + 1) * BK_SLACK) * 4);
  unsigned int* pairs  = (unsigned int*)alloc((size_t)E * 4);
  int*          histG  = (int*)alloc((size_t)KMAX * G_SC * 4);
  int*          offs   = (int*)alloc((size_t)KMAX * G_SC * 4);
  int*          btot   = (int*)alloc(KMAX * 4);
  int*          bbase  = (int*)alloc((KMAX + 1) * 4);
  _Float16*     wp1    = (_Float16*)alloc(128 * 64 * 2);
  _Float16*     wp2    = (_Float16*)alloc(64 * 128 * 2);
  _Float16*     wp3    = (_Float16*)alloc(128 * 64 * 2);
  _Float16*     wp4    = (_Float16*)alloc(64 * 32 * 2);
  _Float16*     wp5    = (_Float16*)alloc(32 * 16 * 2);
  __half*       bufA   = (__half*)alloc((size_t)(N + 64) * 128 * 2);
  __half*       bufB   = (__half*)alloc((size_t)(N + 64) * 128 * 2);
  (void)ws_size; (void)n_in; (void)out_size;

  const int chunk = (((E + G_SC - 1) / G_SC) + 3) & ~3;  // 4-aligned for int4 reads

  // CSR build (padded colidx; vectorized edge streams)
  k_zero_int<<<2, TPB, 0, stream>>>(btot, KMAX);
  k_hist<<<G_SC, TPB, 0, stream>>>(dst, histG, btot, E, K, chunk);
  k_bbase<<<1, KMAX, 0, stream>>>(btot, bbase, K);
  k_offs<<<K, G_SC, 0, stream>>>(histG, bbase, offs);
  k_scatter<<<G_SC, TPB, 0, stream>>>(src, dst, offs, pairs, E, K, chunk);
  k_bucket_sort<<<K, TPB, 0, stream>>>(pairs, bbase, rowptr, rowend, colidx, dinv, N, E);

  // pack weights + zero bufA's F=64 sentinel row
  k_packAll<<<(27144 + TPB - 1) / TPB, TPB, 0, stream>>>(w1, wp1, w2, wp2, w3, wp3, w4, wp4, w5, wp5, bufA, N);

  int gRow = (N + 63) / 64;
  // L1: LDS-staged MFMA GEMM(128->64)*dinv -> bufB; AGG+BN1+ReLU emit *dinv -> bufA
  k_mgemm1<<<gRow, TPB, 0, stream>>>(x, wp1, dinv, bufB, N);
  k_agg<64, 2, __half><<<(N + 31) / 32, TPB, 0, stream>>>(bufB, rowptr, rowend, colidx, dinv, b1, g1, be1, m1, v1, bufA, N);
  // L2: AGG(64) plain -> bufB; fused GEMM chain 64->128(BN2,ReLU)->64 *dinv -> bufA
  k_agg<64, 3, __half><<<(N + 31) / 32, TPB, 0, stream>>>(bufA, rowptr, rowend, colidx, dinv, nullptr, nullptr, nullptr, nullptr, nullptr, bufB, N);
  k_mgemm23<<<gRow, TPB, 0, stream>>>(bufB, wp2, wp3, dinv, b2, g2, be2, m2, v2, bufA, N);
  // L3: AGG+BN3+ReLU -> bufB; L4 GEMM(64->32)*dinv -> bufA
  k_agg<64, 1, __half><<<(N + 31) / 32, TPB, 0, stream>>>(bufA, rowptr, rowend, colidx, dinv, b3, g3, be3, m3, v3, bufB, N);
  k_mgemm<64, 32><<<gRow, TPB, 0, stream>>>(bufB, wp4, dinv, bufA, N);
  // L4 agg + BN4 + L5 GEMM(32->16)*dinv fused -> bufB
  k_aggemm5<<<gRow, TPB, 0, stream>>>(bufA, rowptr, rowend, colidx, wp5, dinv, b4, g4, be4, m4, v4, bufB, N);
  // final agg(16) + bias -> f32 out
  k_agg<16, 0, float><<<(N + 127) / 128, TPB, 0, stream>>>(bufB, rowptr, rowend, colidx, dinv, b5, nullptr, nullptr, nullptr, nullptr, out, N);
}

// Round 11
// 349.592 us; speedup vs baseline: 1.0421x; 1.0215x over previous
//
#include <hip/hip_runtime.h>
#include <hip/hip_fp16.h>

#define BEPS 1e-5f
static constexpr int TPB = 256;
static constexpr int G_SC = 512;      // scatter workgroups
static constexpr int BK_SHIFT = 8;    // bucket = 256-node range
static constexpr int BK_NODES = 256;
static constexpr int KMAX = 512;      // max buckets (N <= 131072)
static constexpr int BK_SLACK = 2048; // per-bucket colidx padding slack
static constexpr int PACK_ITEMS = 27144;
static constexpr int PACK_BLOCKS = (PACK_ITEMS + TPB - 1) / TPB;

union F4H8 { float4 f4; __half2 h2[4]; };  // 16B = 8 halfs

typedef _Float16 half8 __attribute__((ext_vector_type(8)));
typedef float floatx4 __attribute__((ext_vector_type(4)));

// ================= W pack helper =================
__device__ inline void packone(const float* __restrict__ W, _Float16* __restrict__ Wp,
                               int i, int FO) {
  int j = i & 7, lane = (i >> 3) & 63, tile = i >> 9;
  int nct = FO >> 4, ct = tile % nct, kch = tile / nct;
  int k = kch * 32 + ((lane >> 4) << 3) + j;
  int n = (ct << 4) + (lane & 15);
  Wp[i] = (_Float16)W[k * FO + n];
}

// ================= CSR build: two-level bucket counting sort =================
// k_hist also hosts the weight-pack + sentinel-zero blocks (grid tail) to save
// a launch. btot zeroed by hipMemsetAsync before this kernel.
__global__ __launch_bounds__(TPB) void k_hist(const int* __restrict__ dst,
                                              int* __restrict__ histG,
                                              int* __restrict__ btot,
                                              int E, int K, int chunk,
                                              const float* w1, _Float16* p1,
                                              const float* w2, _Float16* p2,
                                              const float* w3, _Float16* p3,
                                              const float* w4, _Float16* p4,
                                              const float* w5, _Float16* p5,
                                              __half* bufA, int N) {
  if (blockIdx.x >= G_SC) {  // pack tail
    int i = (blockIdx.x - G_SC) * TPB + threadIdx.x;
    if (i < 8192) packone(w1, p1, i, 64);
    else if (i < 16384) packone(w2, p2, i - 8192, 128);
    else if (i < 24576) packone(w3, p3, i - 16384, 64);
    else if (i < 26624) packone(w4, p4, i - 24576, 32);
    else if (i < 27136) packone(w5, p5, i - 26624, 16);
    else if (i < 27144) {  // zero bufA's F=64 sentinel row N
      float4 z = {0.f, 0.f, 0.f, 0.f};
      reinterpret_cast<float4*>(bufA + (size_t)64 * N)[i - 27136] = z;
    }
    return;
  }
  __shared__ int lh[KMAX];
  int g = blockIdx.x, t = threadIdx.x;
  for (int i = t; i < KMAX; i += TPB) lh[i] = 0;
  __syncthreads();
  int e0 = g * chunk, e1 = min(E, e0 + chunk);
  for (int e = e0 + t * 4; e < e1; e += TPB * 4) {
    if (e + 4 <= e1) {
      int4 d4 = *reinterpret_cast<const int4*>(dst + e);
      atomicAdd(&lh[d4.x >> BK_SHIFT], 1);
      atomicAdd(&lh[d4.y >> BK_SHIFT], 1);
      atomicAdd(&lh[d4.z >> BK_SHIFT], 1);
      atomicAdd(&lh[d4.w >> BK_SHIFT], 1);
    } else {
      for (int q = e; q < e1; ++q) atomicAdd(&lh[dst[q] >> BK_SHIFT], 1);
    }
  }
  __syncthreads();
  for (int i = t; i < K; i += TPB) {
    histG[i * G_SC + g] = lh[i];
    atomicAdd(&btot[i], lh[i]);
  }
}

__global__ __launch_bounds__(KMAX) void k_bbase(const int* __restrict__ btot,
                                                int* __restrict__ bbase, int K) {
  __shared__ int sh[KMAX];
  int t = threadIdx.x;
  int v = (t < K) ? btot[t] : 0;
  sh[t] = v;
  __syncthreads();
  for (int s = 1; s < KMAX; s <<= 1) {
    int x = sh[t];
    int y = (t >= s) ? sh[t - s] : 0;
    __syncthreads();
    sh[t] = x + y;
    __syncthreads();
  }
  if (t < K) bbase[t] = sh[t] - v;
  if (t == 0) bbase[K] = sh[K - 1];
}

__global__ __launch_bounds__(G_SC) void k_offs(const int* __restrict__ histG,
                                               const int* __restrict__ bbase,
                                               int* __restrict__ offs) {
  __shared__ int sh[G_SC];
  int b = blockIdx.x, t = threadIdx.x;
  int v = histG[b * G_SC + t];
  sh[t] = v;
  __syncthreads();
  for (int s = 1; s < G_SC; s <<= 1) {
    int x = sh[t];
    int y = (t >= s) ? sh[t - s] : 0;
    __syncthreads();
    sh[t] = x + y;
    __syncthreads();
  }
  offs[b * G_SC + t] = bbase[b] + sh[t] - v;
}

__global__ __launch_bounds__(TPB) void k_scatter(const int* __restrict__ src,
                                                 const int* __restrict__ dst,
                                                 const int* __restrict__ offs,
                                                 unsigned int* __restrict__ pairs,
                                                 int E, int K, int chunk) {
  __shared__ int cur[KMAX];
  int g = blockIdx.x, t = threadIdx.x;
  for (int i = t; i < K; i += TPB) cur[i] = offs[i * G_SC + g];
  __syncthreads();
  int e0 = g * chunk, e1 = min(E, e0 + chunk);
  for (int e = e0 + t * 4; e < e1; e += TPB * 4) {
    if (e + 4 <= e1) {
      int4 d4 = *reinterpret_cast<const int4*>(dst + e);
      int4 s4 = *reinterpret_cast<const int4*>(src + e);
      int p0 = atomicAdd(&cur[d4.x >> BK_SHIFT], 1);
      pairs[p0] = (unsigned int)s4.x | ((unsigned int)(d4.x & (BK_NODES - 1)) << 20);
      int p1 = atomicAdd(&cur[d4.y >> BK_SHIFT], 1);
      pairs[p1] = (unsigned int)s4.y | ((unsigned int)(d4.y & (BK_NODES - 1)) << 20);
      int p2 = atomicAdd(&cur[d4.z >> BK_SHIFT], 1);
      pairs[p2] = (unsigned int)s4.z | ((unsigned int)(d4.z & (BK_NODES - 1)) << 20);
      int p3 = atomicAdd(&cur[d4.w >> BK_SHIFT], 1);
      pairs[p3] = (unsigned int)s4.w | ((unsigned int)(d4.w & (BK_NODES - 1)) << 20);
    } else {
      for (int q = e; q < e1; ++q) {
        int d = dst[q];
        int pos = atomicAdd(&cur[d >> BK_SHIFT], 1);
        pairs[pos] = (unsigned int)src[q] | ((unsigned int)(d & (BK_NODES - 1)) << 20);
      }
    }
  }
}

// per-bucket LDS counting sort -> PADDED colidx (lists padded to multiple of 8
// with sentinel N -> zero row; 8-aligned starts; tail-free agg loops).
__global__ __launch_bounds__(TPB) void k_bucket_sort(const unsigned int* __restrict__ pairs,
                                                     const int* __restrict__ bbase,
                                                     int* __restrict__ rowptr,
                                                     int* __restrict__ rowend,
                                                     int* __restrict__ colidx,
                                                     float* __restrict__ dinv,
                                                     int N, int E) {
  __shared__ int cur[BK_NODES];
  __shared__ int sh[BK_NODES];
  int b = blockIdx.x, t = threadIdx.x;
  int base = bbase[b], end = bbase[b + 1];
  int n0 = b << BK_SHIFT;
  int nNodes = min(BK_NODES, N - n0);
  cur[t] = 0;
  __syncthreads();
  for (int e = base + t; e < end; e += TPB) atomicAdd(&cur[pairs[e] >> 20], 1);
  __syncthreads();
  int v = cur[t];                 // raw degree
  int pd = (v + 7) & ~7;          // padded degree
  sh[t] = pd;
  __syncthreads();
  for (int s = 1; s < TPB; s <<= 1) {
    int x = sh[t];
    int y = (t >= s) ? sh[t - s] : 0;
    __syncthreads();
    sh[t] = x + y;
    __syncthreads();
  }
  int Bb = (base + b * BK_SLACK + 7) & ~7;
  int start = Bb + (sh[t] - pd);
  if (t < nNodes) {
    rowptr[n0 + t] = start;
    rowend[n0 + t] = start + pd;
    dinv[n0 + t] = rsqrtf((float)(v + 1));
    for (int i = start + v; i < start + pd; ++i) colidx[i] = N;  // pads -> zero row
  }
  __syncthreads();
  cur[t] = start;
  __syncthreads();
  for (int e = base + t; e < end; e += TPB) {
    unsigned int p = pairs[e];
    int pos = atomicAdd(&cur[p >> 20], 1);
    colidx[pos] = (int)(p & 0xFFFFFu);
  }
}

// ================= L1 MFMA GEMM, LDS-staged x (128 -> 64, *dinv) =============
__global__ __launch_bounds__(TPB) void k_mgemm1(const float* __restrict__ x,
                                                const _Float16* __restrict__ Wp,
                                                const float* __restrict__ dinv,
                                                __half* __restrict__ out, int N) {
  __shared__ float4 Wsh[4 * 4 * 64];       // 128x64 fp16 = 16 KB
  __shared__ _Float16 xs[64 * 136];        // 17.4 KB staged fp16 x-tile
  for (int i = threadIdx.x; i < 1024; i += TPB)
    Wsh[i] = reinterpret_cast<const float4*>(Wp)[i];
  int rowBase = blockIdx.x * 64;
  for (int i = threadIdx.x; i < 2048; i += TPB) {  // 64 rows x 32 float4, coalesced
    int r = i >> 5, c4 = i & 31;
    int gr = rowBase + r;
    float4 f = {0.f, 0.f, 0.f, 0.f};
    if (gr < N) f = reinterpret_cast<const float4*>(x)[(size_t)gr * 32 + c4];
    _Float16* p = &xs[r * 136 + c4 * 4];
    p[0] = (_Float16)f.x; p[1] = (_Float16)f.y; p[2] = (_Float16)f.z; p[3] = (_Float16)f.w;
  }
  __syncthreads();

  int lane = threadIdx.x & 63;
  int wv = threadIdx.x >> 6;
  int quad = lane >> 4;
  int m = lane & 15;
  int lrow = wv * 16 + m;

  floatx4 acc[4];
#pragma unroll
  for (int ct = 0; ct < 4; ++ct) acc[ct] = (floatx4){0.f, 0.f, 0.f, 0.f};
#pragma unroll
  for (int kch = 0; kch < 4; ++kch) {
    half8 a = *reinterpret_cast<const half8*>(&xs[lrow * 136 + kch * 32 + quad * 8]);
#pragma unroll
    for (int ct = 0; ct < 4; ++ct) {
      union { float4 f4; half8 h8; } ub;
      ub.f4 = Wsh[(kch * 4 + ct) * 64 + lane];
      acc[ct] = __builtin_amdgcn_mfma_f32_16x16x32_f16(a, ub.h8, acc[ct], 0, 0, 0);
    }
  }
  int r0 = rowBase + wv * 16 + quad * 4;
  float dv[4];
#pragma unroll
  for (int reg = 0; reg < 4; ++reg) dv[reg] = (r0 + reg < N) ? dinv[r0 + reg] : 0.f;
#pragma unroll
  for (int ct = 0; ct < 4; ++ct) {
    int col = ct * 16 + m;
#pragma unroll
    for (int reg = 0; reg < 4; ++reg) {
      int r = r0 + reg;
      out[(size_t)r * 64 + col] = __float2half(acc[ct][reg] * dv[reg]);
    }
  }
}

// ====== Agg(64) into LDS tile with the GOOD gather shape (8 lanes/row) =======
// Block covers 64 rows in 2 passes of 32 rows x 8 lanes. Output fp16 into
// tr (pitch 136 halfs). DO_BN=0: val*dinv (MODE3). DO_BN=1: relu(bn(...))
// after *dinv (MODE1). Rows >= N produce zeros.
template <int DO_BN>
__device__ inline void agg_to_lds64(const float4* __restrict__ in16,
                                    const int* __restrict__ rowptr,
                                    const int* __restrict__ rowend,
                                    const int* __restrict__ colidx,
                                    const float* __restrict__ dinv,
                                    const float* __restrict__ B_,
                                    const float* __restrict__ G_,
                                    const float* __restrict__ Be_,
                                    const float* __restrict__ M_,
                                    const float* __restrict__ V_,
                                    int rowBase, int N, _Float16* __restrict__ tr) {
#pragma unroll
  for (int pass = 0; pass < 2; ++pass) {
    int lr = pass * 32 + (int)(threadIdx.x >> 3);
    int lane = threadIdx.x & 7;
    int node = rowBase + lr;
    bool valid = node < N;
    int rd = valid ? node : N;
    float acc[8];
    {
      F4H8 u;
      u.f4 = in16[(size_t)rd * 8 + lane];
#pragma unroll
      for (int i = 0; i < 4; ++i) {
        float2 t2 = __half22float2(u.h2[i]);
        acc[2 * i] = t2.x;
        acc[2 * i + 1] = t2.y;
      }
    }
    int e0 = valid ? rowptr[node] : 0;
    int e1 = valid ? rowend[node] : 0;
    int e = e0;
    for (; e + 16 <= e1; e += 16) {
      int4 c0 = *reinterpret_cast<const int4*>(colidx + e);
      int4 c1 = *reinterpret_cast<const int4*>(colidx + e + 4);
      int4 c2 = *reinterpret_cast<const int4*>(colidx + e + 8);
      int4 c3 = *reinterpret_cast<const int4*>(colidx + e + 12);
      F4H8 u[16];
      u[0].f4  = in16[(size_t)c0.x * 8 + lane];
      u[1].f4  = in16[(size_t)c0.y * 8 + lane];
      u[2].f4  = in16[(size_t)c0.z * 8 + lane];
      u[3].f4  = in16[(size_t)c0.w * 8 + lane];
      u[4].f4  = in16[(size_t)c1.x * 8 + lane];
      u[5].f4  = in16[(size_t)c1.y * 8 + lane];
      u[6].f4  = in16[(size_t)c1.z * 8 + lane];
      u[7].f4  = in16[(size_t)c1.w * 8 + lane];
      u[8].f4  = in16[(size_t)c2.x * 8 + lane];
      u[9].f4  = in16[(size_t)c2.y * 8 + lane];
      u[10].f4 = in16[(size_t)c2.z * 8 + lane];
      u[11].f4 = in16[(size_t)c2.w * 8 + lane];
      u[12].f4 = in16[(size_t)c3.x * 8 + lane];
      u[13].f4 = in16[(size_t)c3.y * 8 + lane];
      u[14].f4 = in16[(size_t)c3.z * 8 + lane];
      u[15].f4 = in16[(size_t)c3.w * 8 + lane];
#pragma unroll
      for (int q = 0; q < 16; ++q) {
#pragma unroll
        for (int i = 0; i < 4; ++i) {
          float2 t2 = __half22float2(u[q].h2[i]);
          acc[2 * i] += t2.x;
          acc[2 * i + 1] += t2.y;
        }
      }
    }
    if (e < e1) {
      int4 c0 = *reinterpret_cast<const int4*>(colidx + e);
      int4 c1 = *reinterpret_cast<const int4*>(colidx + e + 4);
      F4H8 u[8];
      u[0].f4 = in16[(size_t)c0.x * 8 + lane];
      u[1].f4 = in16[(size_t)c0.y * 8 + lane];
      u[2].f4 = in16[(size_t)c0.z * 8 + lane];
      u[3].f4 = in16[(size_t)c0.w * 8 + lane];
      u[4].f4 = in16[(size_t)c1.x * 8 + lane];
      u[5].f4 = in16[(size_t)c1.y * 8 + lane];
      u[6].f4 = in16[(size_t)c1.z * 8 + lane];
      u[7].f4 = in16[(size_t)c1.w * 8 + lane];
#pragma unroll
      for (int q = 0; q < 8; ++q) {
#pragma unroll
        for (int i = 0; i < 4; ++i) {
          float2 t2 = __half22float2(u[q].h2[i]);
          acc[2 * i] += t2.x;
          acc[2 * i + 1] += t2.y;
        }
      }
    }
    float dv = valid ? dinv[node] : 0.f;
#pragma unroll
    for (int i = 0; i < 8; ++i) acc[i] *= dv;
    if (DO_BN) {
      const float4* B = reinterpret_cast<const float4*>(B_);
      const float4* G = reinterpret_cast<const float4*>(G_);
      const float4* Be = reinterpret_cast<const float4*>(Be_);
      const float4* M = reinterpret_cast<const float4*>(M_);
      const float4* Vv = reinterpret_cast<const float4*>(V_);
#pragma unroll
      for (int h = 0; h < 2; ++h) {
        float4 b4 = B[lane * 2 + h], g4 = G[lane * 2 + h], e4 = Be[lane * 2 + h];
        float4 m4 = M[lane * 2 + h], v4 = Vv[lane * 2 + h];
        float* a = acc + 4 * h;
        a[0] = fmaxf((a[0] + b4.x - m4.x) * (g4.x * rsqrtf(v4.x + BEPS)) + e4.x, 0.f);
        a[1] = fmaxf((a[1] + b4.y - m4.y) * (g4.y * rsqrtf(v4.y + BEPS)) + e4.y, 0.f);
        a[2] = fmaxf((a[2] + b4.z - m4.z) * (g4.z * rsqrtf(v4.z + BEPS)) + e4.z, 0.f);
        a[3] = fmaxf((a[3] + b4.w - m4.w) * (g4.w * rsqrtf(v4.w + BEPS)) + e4.w, 0.f);
      }
    }
    F4H8 o;
#pragma unroll
    for (int i = 0; i < 4; ++i) o.h2[i] = __floats2half2_rn(acc[2 * i], acc[2 * i + 1]);
    *reinterpret_cast<float4*>(&tr[lr * 136 + lane * 8]) = o.f4;
  }
}

// ====== Fused L2: agg(64, plain) -> 64->128 BN2/ReLU -> 128->64 *dinv ========
// Agg lands in LDS tile tr (good gather shape); MFMA1 consumes tr into regs;
// tr is then reused (after barrier) for the h2 transpose staging.
__global__ __launch_bounds__(TPB) void k_aggemm23(const __half* __restrict__ hin,
                                                  const int* __restrict__ rowptr,
                                                  const int* __restrict__ rowend,
                                                  const int* __restrict__ colidx,
                                                  const _Float16* __restrict__ W2p,
                                                  const _Float16* __restrict__ W3p,
                                                  const float* __restrict__ dinv,
                                                  const float* __restrict__ b2,
                                                  const float* __restrict__ g2,
                                                  const float* __restrict__ be2,
                                                  const float* __restrict__ m2,
                                                  const float* __restrict__ v2,
                                                  __half* __restrict__ out, int N) {
  __shared__ float4 W2s[2 * 8 * 64];       // 16 KB
  __shared__ float4 W3s[4 * 4 * 64];       // 16 KB
  __shared__ _Float16 tr[64 * 136];        // 17.4 KB (agg out, then h2 transpose)
  for (int i = threadIdx.x; i < 1024; i += TPB) W2s[i] = reinterpret_cast<const float4*>(W2p)[i];
  for (int i = threadIdx.x; i < 1024; i += TPB) W3s[i] = reinterpret_cast<const float4*>(W3p)[i];
  int rowBase = blockIdx.x * 64;
  agg_to_lds64<0>(reinterpret_cast<const float4*>(hin), rowptr, rowend, colidx, dinv,
                  nullptr, nullptr, nullptr, nullptr, nullptr, rowBase, N, tr);
  __syncthreads();

  int lane = threadIdx.x & 63;
  int wv = threadIdx.x >> 6;
  int quad = lane >> 4;
  int m = lane & 15;

  floatx4 acc1[8];
#pragma unroll
  for (int ct = 0; ct < 8; ++ct) acc1[ct] = (floatx4){0.f, 0.f, 0.f, 0.f};
#pragma unroll
  for (int kch = 0; kch < 2; ++kch) {
    half8 a = *reinterpret_cast<const half8*>(&tr[(wv * 16 + m) * 136 + kch * 32 + quad * 8]);
#pragma unroll
    for (int ct = 0; ct < 8; ++ct) {
      union { float4 f4; half8 h8; } ub;
      ub.f4 = W2s[(kch * 8 + ct) * 64 + lane];
      acc1[ct] = __builtin_amdgcn_mfma_f32_16x16x32_f16(a, ub.h8, acc1[ct], 0, 0, 0);
    }
  }
  __syncthreads();  // all waves done reading tr before overwrite
  _Float16* mytr = tr + (size_t)wv * 16 * 136;
#pragma unroll
  for (int ct = 0; ct < 8; ++ct) {
    int col = ct * 16 + m;
    float sc = g2[col] * rsqrtf(v2[col] + BEPS);
    float bb = b2[col] - m2[col];
    float ee = be2[col];
#pragma unroll
    for (int reg = 0; reg < 4; ++reg) {
      int r = quad * 4 + reg;
      mytr[r * 136 + col] = (_Float16)fmaxf((acc1[ct][reg] + bb) * sc + ee, 0.f);
    }
  }
  floatx4 acc2[4];
#pragma unroll
  for (int ct = 0; ct < 4; ++ct) acc2[ct] = (floatx4){0.f, 0.f, 0.f, 0.f};
#pragma unroll
  for (int kch = 0; kch < 4; ++kch) {
    half8 a2 = *reinterpret_cast<const half8*>(&mytr[m * 136 + kch * 32 + quad * 8]);
#pragma unroll
    for (int ct = 0; ct < 4; ++ct) {
      union { float4 f4; half8 h8; } ub;
      ub.f4 = W3s[(kch * 4 + ct) * 64 + lane];
      acc2[ct] = __builtin_amdgcn_mfma_f32_16x16x32_f16(a2, ub.h8, acc2[ct], 0, 0, 0);
    }
  }
  int r0 = rowBase + wv * 16 + quad * 4;
  float dv[4];
#pragma unroll
  for (int reg = 0; reg < 4; ++reg) dv[reg] = (r0 + reg < N) ? dinv[r0 + reg] : 0.f;
#pragma unroll
  for (int ct = 0; ct < 4; ++ct) {
    int col = ct * 16 + m;
#pragma unroll
    for (int reg = 0; reg < 4; ++reg) {
      int r = r0 + reg;
      out[(size_t)r * 64 + col] = __float2half(acc2[ct][reg] * dv[reg]);
    }
  }
}

// ====== Fused L3 agg(BN3/ReLU) + L4 GEMM(64->32)*dinv ========================
__global__ __launch_bounds__(TPB) void k_aggemm34(const __half* __restrict__ hin,
                                                  const int* __restrict__ rowptr,
                                                  const int* __restrict__ rowend,
                                                  const int* __restrict__ colidx,
                                                  const _Float16* __restrict__ W4p,
                                                  const float* __restrict__ dinv,
                                                  const float* __restrict__ b_,
                                                  const float* __restrict__ g_,
                                                  const float* __restrict__ be_,
                                                  const float* __restrict__ m_,
                                                  const float* __restrict__ v_,
                                                  __half* __restrict__ out, int N) {
  __shared__ float4 W4s[2 * 2 * 64];       // 64x32 fp16 = 4 KB
  __shared__ _Float16 tr[64 * 136];        // 17.4 KB
  for (int i = threadIdx.x; i < 256; i += TPB) W4s[i] = reinterpret_cast<const float4*>(W4p)[i];
  int rowBase = blockIdx.x * 64;
  agg_to_lds64<1>(reinterpret_cast<const float4*>(hin), rowptr, rowend, colidx, dinv,
                  b_, g_, be_, m_, v_, rowBase, N, tr);
  __syncthreads();

  int lane = threadIdx.x & 63;
  int wv = threadIdx.x >> 6;
  int quad = lane >> 4;
  int m = lane & 15;

  floatx4 acc[2];
#pragma unroll
  for (int ct = 0; ct < 2; ++ct) acc[ct] = (floatx4){0.f, 0.f, 0.f, 0.f};
#pragma unroll
  for (int kch = 0; kch < 2; ++kch) {
    half8 a = *reinterpret_cast<const half8*>(&tr[(wv * 16 + m) * 136 + kch * 32 + quad * 8]);
#pragma unroll
    for (int ct = 0; ct < 2; ++ct) {
      union { float4 f4; half8 h8; } ub;
      ub.f4 = W4s[(kch * 2 + ct) * 64 + lane];
      acc[ct] = __builtin_amdgcn_mfma_f32_16x16x32_f16(a, ub.h8, acc[ct], 0, 0, 0);
    }
  }
  int r0 = rowBase + wv * 16 + quad * 4;
  float dv[4];
#pragma unroll
  for (int reg = 0; reg < 4; ++reg) dv[reg] = (r0 + reg < N) ? dinv[r0 + reg] : 0.f;
#pragma unroll
  for (int ct = 0; ct < 2; ++ct) {
    int col = ct * 16 + m;
#pragma unroll
    for (int reg = 0; reg < 4; ++reg) {
      int r = r0 + reg;
      out[(size_t)r * 32 + col] = __float2half(acc[ct][reg] * dv[reg]);
    }
  }
}

// ====== Fused agg(BN4)+GEMM, FI=32 -> FO=16 ======
__global__ __launch_bounds__(TPB) void k_aggemm5(const __half* __restrict__ hin,
                                                 const int* __restrict__ rowptr,
                                                 const int* __restrict__ rowend,
                                                 const int* __restrict__ colidx,
                                                 const _Float16* __restrict__ Wp,
                                                 const float* __restrict__ dinv,
                                                 const float* __restrict__ b_,
                                                 const float* __restrict__ g_,
                                                 const float* __restrict__ be_,
                                                 const float* __restrict__ m_,
                                                 const float* __restrict__ v_,
                                                 __half* __restrict__ out, int N) {
  __shared__ float4 Wsh[64];  // 32x16 fp16 = 1 KB
  if (threadIdx.x < 64) Wsh[threadIdx.x] = reinterpret_cast<const float4*>(Wp)[threadIdx.x];
  __syncthreads();

  int lane = threadIdx.x & 63;
  int wv = threadIdx.x >> 6;
  int quad = lane >> 4;
  int m = lane & 15;
  int rowBase = blockIdx.x * 64 + wv * 16;
  int node = rowBase + m;
  bool valid = node < N;
  int rd = valid ? node : N;
  int e0 = valid ? rowptr[node] : 0;
  int e1 = valid ? rowend[node] : 0;
  const float4* in16 = reinterpret_cast<const float4*>(hin);

  float acc[8];
  {
    F4H8 u;
    u.f4 = in16[(size_t)rd * 4 + quad];
#pragma unroll
    for (int i = 0; i < 4; ++i) {
      float2 t2 = __half22float2(u.h2[i]);
      acc[2 * i] = t2.x;
      acc[2 * i + 1] = t2.y;
    }
  }
  for (int e = e0; e < e1; e += 4) {
    int4 c = *reinterpret_cast<const int4*>(colidx + e);
    F4H8 u0, u1, u2, u3;
    u0.f4 = in16[(size_t)c.x * 4 + quad];
    u1.f4 = in16[(size_t)c.y * 4 + quad];
    u2.f4 = in16[(size_t)c.z * 4 + quad];
    u3.f4 = in16[(size_t)c.w * 4 + quad];
#pragma unroll
    for (int i = 0; i < 4; ++i) {
      float2 a = __half22float2(u0.h2[i]), b = __half22float2(u1.h2[i]);
      float2 cc = __half22float2(u2.h2[i]), d = __half22float2(u3.h2[i]);
      acc[2 * i] += (a.x + b.x) + (cc.x + d.x);
      acc[2 * i + 1] += (a.y + b.y) + (cc.y + d.y);
    }
  }
  float dvn = valid ? dinv[node] : 0.f;
  half8 afr;
#pragma unroll
  for (int j = 0; j < 8; ++j) {
    int f = quad * 8 + j;
    float sc = g_[f] * rsqrtf(v_[f] + BEPS);
    float val = fmaxf((acc[j] * dvn + b_[f] - m_[f]) * sc + be_[f], 0.f);
    afr[j] = (_Float16)val;
  }
  floatx4 c0 = (floatx4){0.f, 0.f, 0.f, 0.f};
  union { float4 f4; half8 h8; } ub;
  ub.f4 = Wsh[lane];
  c0 = __builtin_amdgcn_mfma_f32_16x16x32_f16(afr, ub.h8, c0, 0, 0, 0);
  int r0 = blockIdx.x * 64 + wv * 16 + quad * 4;
#pragma unroll
  for (int reg = 0; reg < 4; ++reg) {
    int r = r0 + reg;
    float dv = (r < N) ? dinv[r] : 0.f;
    out[(size_t)r * 16 + m] = __float2half(c0[reg] * dv);
  }
}

// ================= Standalone aggregation (agg1 MODE2, final MODE0) ==========
template <int F, int MODE, typename TO>
__global__ __launch_bounds__(TPB) void k_agg(const __half* __restrict__ in,
                                             const int* __restrict__ rowptr,
                                             const int* __restrict__ rowend,
                                             const int* __restrict__ colidx,
                                             const float* __restrict__ dinv,
                                             const float* __restrict__ bias,
                                             const float* __restrict__ g,
                                             const float* __restrict__ be,
                                             const float* __restrict__ m,
                                             const float* __restrict__ v,
                                             TO* __restrict__ out, int N) {
  constexpr int V = F / 8;
  constexpr int NPB = TPB / V;
  int node = blockIdx.x * NPB + (int)(threadIdx.x / V);
  int lane = threadIdx.x % V;
  if (node >= N) return;
  const float4* in16 = reinterpret_cast<const float4*>(in);
  const size_t rs = F / 8;
  float acc[8];
  {
    F4H8 u;
    u.f4 = in16[(size_t)node * rs + lane];
#pragma unroll
    for (int i = 0; i < 4; ++i) {
      float2 t2 = __half22float2(u.h2[i]);
      acc[2 * i] = t2.x;
      acc[2 * i + 1] = t2.y;
    }
  }
  int e0 = rowptr[node], e1 = rowend[node];
  int e = e0;
  for (; e + 16 <= e1; e += 16) {
    int4 c0 = *reinterpret_cast<const int4*>(colidx + e);
    int4 c1 = *reinterpret_cast<const int4*>(colidx + e + 4);
    int4 c2 = *reinterpret_cast<const int4*>(colidx + e + 8);
    int4 c3 = *reinterpret_cast<const int4*>(colidx + e + 12);
    F4H8 u[16];
    u[0].f4  = in16[(size_t)c0.x * rs + lane];
    u[1].f4  = in16[(size_t)c0.y * rs + lane];
    u[2].f4  = in16[(size_t)c0.z * rs + lane];
    u[3].f4  = in16[(size_t)c0.w * rs + lane];
    u[4].f4  = in16[(size_t)c1.x * rs + lane];
    u[5].f4  = in16[(size_t)c1.y * rs + lane];
    u[6].f4  = in16[(size_t)c1.z * rs + lane];
    u[7].f4  = in16[(size_t)c1.w * rs + lane];
    u[8].f4  = in16[(size_t)c2.x * rs + lane];
    u[9].f4  = in16[(size_t)c2.y * rs + lane];
    u[10].f4 = in16[(size_t)c2.z * rs + lane];
    u[11].f4 = in16[(size_t)c2.w * rs + lane];
    u[12].f4 = in16[(size_t)c3.x * rs + lane];
    u[13].f4 = in16[(size_t)c3.y * rs + lane];
    u[14].f4 = in16[(size_t)c3.z * rs + lane];
    u[15].f4 = in16[(size_t)c3.w * rs + lane];
#pragma unroll
    for (int q = 0; q < 16; ++q) {
#pragma unroll
      for (int i = 0; i < 4; ++i) {
        float2 t2 = __half22float2(u[q].h2[i]);
        acc[2 * i] += t2.x;
        acc[2 * i + 1] += t2.y;
      }
    }
  }
  if (e < e1) {
    int4 c0 = *reinterpret_cast<const int4*>(colidx + e);
    int4 c1 = *reinterpret_cast<const int4*>(colidx + e + 4);
    F4H8 u[8];
    u[0].f4 = in16[(size_t)c0.x * rs + lane];
    u[1].f4 = in16[(size_t)c0.y * rs + lane];
    u[2].f4 = in16[(size_t)c0.z * rs + lane];
    u[3].f4 = in16[(size_t)c0.w * rs + lane];
    u[4].f4 = in16[(size_t)c1.x * rs + lane];
    u[5].f4 = in16[(size_t)c1.y * rs + lane];
    u[6].f4 = in16[(size_t)c1.z * rs + lane];
    u[7].f4 = in16[(size_t)c1.w * rs + lane];
#pragma unroll
    for (int q = 0; q < 8; ++q) {
#pragma unroll
      for (int i = 0; i < 4; ++i) {
        float2 t2 = __half22float2(u[q].h2[i]);
        acc[2 * i] += t2.x;
        acc[2 * i + 1] += t2.y;
      }
    }
  }
  float dv = dinv[node];
#pragma unroll
  for (int i = 0; i < 8; ++i) acc[i] *= dv;
  if (MODE == 0) {
    float4 ba = reinterpret_cast<const float4*>(bias)[lane * 2];
    float4 bb = reinterpret_cast<const float4*>(bias)[lane * 2 + 1];
    acc[0] += ba.x; acc[1] += ba.y; acc[2] += ba.z; acc[3] += ba.w;
    acc[4] += bb.x; acc[5] += bb.y; acc[6] += bb.z; acc[7] += bb.w;
  } else if (MODE == 1 || MODE == 2) {
    const float4* B = reinterpret_cast<const float4*>(bias);
    const float4* G = reinterpret_cast<const float4*>(g);
    const float4* Be = reinterpret_cast<const float4*>(be);
    const float4* M = reinterpret_cast<const float4*>(m);
    const float4* Vv = reinterpret_cast<const float4*>(v);
#pragma unroll
    for (int h = 0; h < 2; ++h) {
      float4 b4 = B[lane * 2 + h], g4 = G[lane * 2 + h], e4 = Be[lane * 2 + h];
      float4 m4 = M[lane * 2 + h], v4 = Vv[lane * 2 + h];
      float* a = acc + 4 * h;
      a[0] = fmaxf((a[0] + b4.x - m4.x) * (g4.x * rsqrtf(v4.x + BEPS)) + e4.x, 0.f);
      a[1] = fmaxf((a[1] + b4.y - m4.y) * (g4.y * rsqrtf(v4.y + BEPS)) + e4.y, 0.f);
      a[2] = fmaxf((a[2] + b4.z - m4.z) * (g4.z * rsqrtf(v4.z + BEPS)) + e4.z, 0.f);
      a[3] = fmaxf((a[3] + b4.w - m4.w) * (g4.w * rsqrtf(v4.w + BEPS)) + e4.w, 0.f);
    }
    if (MODE == 2) {
#pragma unroll
      for (int i = 0; i < 8; ++i) acc[i] *= dv;
    }
  }
  if constexpr (sizeof(TO) == 2) {
    F4H8 u;
#pragma unroll
    for (int i = 0; i < 4; ++i) u.h2[i] = __floats2half2_rn(acc[2 * i], acc[2 * i + 1]);
    reinterpret_cast<float4*>(out)[(size_t)node * rs + lane] = u.f4;
  } else {
    float4 o0 = {acc[0], acc[1], acc[2], acc[3]};
    float4 o1 = {acc[4], acc[5], acc[6], acc[7]};
    float4* op = reinterpret_cast<float4*>((float*)out + (size_t)node * F + lane * 8);
    op[0] = o0;
    op[1] = o1;
  }
}

// ================= launch =================

extern "C" void kernel_launch(void* const* d_in, const int* in_sizes, int n_in,
                              void* d_out, int out_size, void* d_ws, size_t ws_size,
                              hipStream_t stream) {
  const float* x = (const float*)d_in[0];
  const int* ei = (const int*)d_in[1];
  const int N = in_sizes[0] / 128;
  const int E = in_sizes[1] / 2;
  const int* src = ei;
  const int* dst = ei + E;

  const float* w1 = (const float*)d_in[2];  const float* b1 = (const float*)d_in[3];
  const float* w2 = (const float*)d_in[4];  const float* b2 = (const float*)d_in[5];
  const float* w3 = (const float*)d_in[6];  const float* b3 = (const float*)d_in[7];
  const float* w4 = (const float*)d_in[8];  const float* b4 = (const float*)d_in[9];
  const float* w5 = (const float*)d_in[10]; const float* b5 = (const float*)d_in[11];
  const float* g1 = (const float*)d_in[12]; const float* be1 = (const float*)d_in[13];
  const float* m1 = (const float*)d_in[14]; const float* v1 = (const float*)d_in[15];
  const float* g2 = (const float*)d_in[16]; const float* be2 = (const float*)d_in[17];
  const float* m2 = (const float*)d_in[18]; const float* v2 = (const float*)d_in[19];
  const float* g3 = (const float*)d_in[20]; const float* be3 = (const float*)d_in[21];
  const float* m3 = (const float*)d_in[22]; const float* v3 = (const float*)d_in[23];
  const float* g4 = (const float*)d_in[24]; const float* be4 = (const float*)d_in[25];
  const float* m4 = (const float*)d_in[26]; const float* v4 = (const float*)d_in[27];
  float* out = (float*)d_out;

  char* ws = (char*)d_ws;
  size_t off = 0;
  auto alloc = [&](size_t bytes) -> void* {
    void* p = ws + off;
    off += (bytes + 255) & ~(size_t)255;
    return p;
  };
  const int K = (N + BK_NODES - 1) >> BK_SHIFT;  // 391 for N=100000
  float*        dinv   = (float*)alloc((size_t)N * 4);
  int*          rowptr = (int*)alloc((size_t)N * 4);
  int*          rowend = (int*)alloc((size_t)N * 4);
  int*          colidx = (int*)alloc(((size_t)E + (size_t)(K + 1) * BK_SLACK) * 4);
  unsigned int* pairs  = (unsigned int*)alloc((size_t)E * 4);
  int*          histG  = (int*)alloc((size_t)KMAX * G_SC * 4);
  int*          offs   = (int*)alloc((size_t)KMAX * G_SC * 4);
  int*          btot   = (int*)alloc(KMAX * 4);
  int*          bbase  = (int*)alloc((KMAX + 1) * 4);
  _Float16*     wp1    = (_Float16*)alloc(128 * 64 * 2);
  _Float16*     wp2    = (_Float16*)alloc(64 * 128 * 2);
  _Float16*     wp3    = (_Float16*)alloc(128 * 64 * 2);
  _Float16*     wp4    = (_Float16*)alloc(64 * 32 * 2);
  _Float16*     wp5    = (_Float16*)alloc(32 * 16 * 2);
  __half*       bufA   = (__half*)alloc((size_t)(N + 64) * 128 * 2);
  __half*       bufB   = (__half*)alloc((size_t)(N + 64) * 128 * 2);
  (void)ws_size; (void)n_in; (void)out_size;

  const int chunk = (((E + G_SC - 1) / G_SC) + 3) & ~3;  // 4-aligned for int4 reads

  // CSR build + weight pack (pack rides k_hist's grid tail)
  hipMemsetAsync(btot, 0, KMAX * 4, stream);
  k_hist<<<G_SC + PACK_BLOCKS, TPB, 0, stream>>>(dst, histG, btot, E, K, chunk,
                                                 w1, wp1, w2, wp2, w3, wp3, w4, wp4, w5, wp5,
                                                 bufA, N);
  k_bbase<<<1, KMAX, 0, stream>>>(btot, bbase, K);
  k_offs<<<K, G_SC, 0, stream>>>(histG, bbase, offs);
  k_scatter<<<G_SC, TPB, 0, stream>>>(src, dst, offs, pairs, E, K, chunk);
  k_bucket_sort<<<K, TPB, 0, stream>>>(pairs, bbase, rowptr, rowend, colidx, dinv, N, E);

  int gRow = (N + 63) / 64;
  // L1: LDS-staged MFMA GEMM(128->64)*dinv -> bufB; AGG+BN1+ReLU emit *dinv -> bufA
  k_mgemm1<<<gRow, TPB, 0, stream>>>(x, wp1, dinv, bufB, N);
  k_agg<64, 2, __half><<<(N + 31) / 32, TPB, 0, stream>>>(bufB, rowptr, rowend, colidx, dinv, b1, g1, be1, m1, v1, bufA, N);
  // L2+L3 fused: agg(64) via LDS -> 64->128 BN2/ReLU -> 128->64 *dinv -> bufB
  k_aggemm23<<<gRow, TPB, 0, stream>>>(bufA, rowptr, rowend, colidx, wp2, wp3, dinv, b2, g2, be2, m2, v2, bufB, N);
  // L3 agg(BN3/ReLU) + L4 GEMM(64->32)*dinv fused -> bufA
  k_aggemm34<<<gRow, TPB, 0, stream>>>(bufB, rowptr, rowend, colidx, wp4, dinv, b3, g3, be3, m3, v3, bufA, N);
  // L4 agg(BN4/ReLU) + L5 GEMM(32->16)*dinv fused -> bufB
  k_aggemm5<<<gRow, TPB, 0, stream>>>(bufA, rowptr, rowend, colidx, wp5, dinv, b4, g4, be4, m4, v4, bufB, N);
  // final agg(16) + bias -> f32 out
  k_agg<16, 0, float><<<(N + 127) / 128, TPB, 0, stream>>>(bufB, rowptr, rowend, colidx, dinv, b5, nullptr, nullptr, nullptr, nullptr, out, N);
}